// Round 1
// baseline (619.297 us; speedup 1.0000x reference)
//
#include <hip/hip_runtime.h>
#include <hip/hip_bf16.h>
#include <math.h>

typedef __bf16 bf16_t;
typedef __attribute__((ext_vector_type(8))) __bf16 bf16x8;
typedef __attribute__((ext_vector_type(4))) float f32x4;

// ---------------------------------------------------------------------------
// mod = t_cond @ adaW + adab    (4 x 6144), all 4 batches per block
// ---------------------------------------------------------------------------
__global__ __launch_bounds__(256) void mod_gemm_kernel(
    const float* __restrict__ tc, const float* __restrict__ adaW,
    const float* __restrict__ adab, float* __restrict__ mod)
{
  __shared__ float st[4][1024];
  int tid = threadIdx.x;
  for (int i = tid; i < 4096; i += 256) st[i >> 10][i & 1023] = tc[i];
  __syncthreads();
  int col = blockIdx.x * 256 + tid;
  float bse = adab[col];
  float a0 = bse, a1 = bse, a2 = bse, a3 = bse;
  for (int c = 0; c < 1024; ++c) {
    float wv = adaW[(size_t)c * 6144 + col];
    a0 = fmaf(st[0][c], wv, a0);
    a1 = fmaf(st[1][c], wv, a1);
    a2 = fmaf(st[2][c], wv, a2);
    a3 = fmaf(st[3][c], wv, a3);
  }
  mod[col] = a0; mod[6144 + col] = a1; mod[2 * 6144 + col] = a2; mod[3 * 6144 + col] = a3;
}

// ---------------------------------------------------------------------------
// Transposing f32 -> bf16 weight prep: out[c][r] = (bf16) in[r][c]
// ---------------------------------------------------------------------------
__global__ __launch_bounds__(256) void transpose_to_bf16(
    const float* __restrict__ in, bf16_t* __restrict__ out, int R, int C)
{
  __shared__ float tile[32][33];
  int c0 = blockIdx.x * 32, r0 = blockIdx.y * 32;
  int tx = threadIdx.x, ty = threadIdx.y;
#pragma unroll
  for (int i = 0; i < 4; ++i)
    tile[ty + i * 8][tx] = in[(size_t)(r0 + ty + i * 8) * C + c0 + tx];
  __syncthreads();
#pragma unroll
  for (int i = 0; i < 4; ++i)
    out[(size_t)(c0 + ty + i * 8) * R + r0 + tx] = (bf16_t)tile[tx][ty + i * 8];
}

// ---------------------------------------------------------------------------
// LayerNorm (+ optional adaLN shift/scale) -> bf16.  One block per row (D=1024).
// ---------------------------------------------------------------------------
__global__ __launch_bounds__(256) void ln_mod_kernel(
    const float* __restrict__ x, const float* __restrict__ wgt,
    const float* __restrict__ mod, int useMod, int shOff, int scOff,
    bf16_t* __restrict__ out)
{
  int row = blockIdx.x;
  int b = row >> 10;
  int tid = threadIdx.x;
  const float* xr = x + (size_t)row * 1024;
  float4 v = ((const float4*)xr)[tid];
  float s = v.x + v.y + v.z + v.w;
  float s2 = v.x * v.x + v.y * v.y + v.z * v.z + v.w * v.w;
#pragma unroll
  for (int off = 32; off > 0; off >>= 1) {
    s += __shfl_down(s, off, 64);
    s2 += __shfl_down(s2, off, 64);
  }
  __shared__ float ps[4], ps2[4];
  if ((tid & 63) == 0) { ps[tid >> 6] = s; ps2[tid >> 6] = s2; }
  __syncthreads();
  float mu = (ps[0] + ps[1] + ps[2] + ps[3]) * (1.0f / 1024.0f);
  float var = (ps2[0] + ps2[1] + ps2[2] + ps2[3]) * (1.0f / 1024.0f) - mu * mu;
  float rs = rsqrtf(var + 1e-5f);
  float xv[4] = {v.x, v.y, v.z, v.w};
#pragma unroll
  for (int i = 0; i < 4; ++i) {
    int col = tid * 4 + i;
    float n = (xv[i] - mu) * rs * wgt[col];
    if (useMod)
      n = n * (1.0f + mod[b * 6144 + scOff + col]) + mod[b * 6144 + shOff + col];
    out[(size_t)row * 1024 + col] = (bf16_t)n;
  }
}

// ---------------------------------------------------------------------------
// RoPE for Q: qf (B,S,H*64) bf16 -> q_r (B,H,S,64) bf16, scaled by 1/sqrt(64)
// ---------------------------------------------------------------------------
__global__ __launch_bounds__(256) void rope_q_kernel(
    const bf16_t* __restrict__ qf, const float* __restrict__ cosq,
    const float* __restrict__ sinq, bf16_t* __restrict__ qr)
{
  int t = blockIdx.x * 256 + threadIdx.x;
  int hd = t & 63;
  int h = (t >> 6) & 15;
  int s = (t >> 10) & 1023;
  int b = t >> 20;
  size_t base = ((size_t)(b * 1024 + s)) * 1024 + h * 64;
  float xv = (float)qf[base + hd];
  int phd = (hd < 32) ? hd + 32 : hd - 32;
  float pv = (float)qf[base + phd];
  float c = cosq[s * 64 + hd], sn = sinq[s * 64 + hd];
  float o = xv * c + ((hd < 32) ? -pv : pv) * sn;
  qr[(((size_t)(b * 16 + h)) * 1024 + s) * 64 + hd] = (bf16_t)(o * 0.125f);
}

// ---------------------------------------------------------------------------
// RoPE for K + relayout of V: kvf (B,K,2*H*64) -> k_r (B,H,K,64), v_t (B,H,64,K)
// ---------------------------------------------------------------------------
__global__ __launch_bounds__(256) void rope_kv_kernel(
    const bf16_t* __restrict__ kvf, const float* __restrict__ cosk,
    const float* __restrict__ sink, bf16_t* __restrict__ kr,
    bf16_t* __restrict__ vt)
{
  int t = blockIdx.x * 256 + threadIdx.x;
  int hd = t & 63;
  int h = (t >> 6) & 15;
  int n = (t >> 10) & 1023;
  int b = t >> 20;
  size_t base = ((size_t)(b * 1024 + n)) * 2048 + h * 64;
  float xv = (float)kvf[base + hd];
  int phd = (hd < 32) ? hd + 32 : hd - 32;
  float pv = (float)kvf[base + phd];
  float c = cosk[n * 64 + hd], sn = sink[n * 64 + hd];
  float o = xv * c + ((hd < 32) ? -pv : pv) * sn;
  int bh = b * 16 + h;
  kr[((size_t)bh * 1024 + n) * 64 + hd] = (bf16_t)o;
  vt[((size_t)bh * 64 + hd) * 1024 + n] = kvf[base + 1024 + hd];
}

// ---------------------------------------------------------------------------
// Flash-style attention with group mask.  One block per (b,h, 64-row Q tile).
// 4 waves; wave w owns S-strip rows [16w,16w+16).  MFMA 16x16x32 bf16.
// ---------------------------------------------------------------------------
__global__ __launch_bounds__(256, 2) void attn_kernel(
    const bf16_t* __restrict__ qr, const bf16_t* __restrict__ kr,
    const bf16_t* __restrict__ vt, const int* __restrict__ grp,
    bf16_t* __restrict__ outp)
{
  __shared__ bf16_t Qs[64 * 72];
  __shared__ bf16_t Ks[64 * 72];
  __shared__ bf16_t Vs[64 * 72];
  __shared__ bf16_t Ps[64 * 72];
  __shared__ int gq[64], gk[64];
  const int bh = blockIdx.x;  // b*16+h
  const int b = bh >> 4;
  const int h = bh & 15;
  const int qBase = blockIdx.y * 64;
  const int tid = threadIdx.x, lane = tid & 63, w = tid >> 6;
  const int l15 = lane & 15, l4 = lane >> 4;
  const f32x4 zero = {0.f, 0.f, 0.f, 0.f};

  // stage Q tile (64x64) + q groups
#pragma unroll
  for (int i = 0; i < 2; ++i) {
    int c = tid * 2 + i;
    int r = c >> 3, cc = (c & 7) * 8;
    *(bf16x8*)(Qs + r * 72 + cc) =
        *(const bf16x8*)(qr + (((size_t)bh) * 1024 + qBase + r) * 64 + cc);
  }
  if (tid < 64) gq[tid] = grp[b * 1024 + qBase + tid];

  f32x4 oacc[4];
  for (int i = 0; i < 4; ++i) oacc[i] = zero;
  float m[4], l[4];
  for (int r = 0; r < 4; ++r) { m[r] = -1e30f; l[r] = 0.f; }

  for (int kt = 0; kt < 16; ++kt) {
    __syncthreads();
#pragma unroll
    for (int i = 0; i < 2; ++i) {
      int c = tid * 2 + i;
      int r = c >> 3, cc = (c & 7) * 8;
      *(bf16x8*)(Ks + r * 72 + cc) =
          *(const bf16x8*)(kr + ((size_t)bh * 1024 + kt * 64 + r) * 64 + cc);
      *(bf16x8*)(Vs + r * 72 + cc) =
          *(const bf16x8*)(vt + ((size_t)bh * 64 + r) * 1024 + kt * 64 + cc);
    }
    if (tid < 64) gk[tid] = grp[b * 1024 + kt * 64 + tid];
    __syncthreads();

    // S = Q K^T  (wave strip 16x64)
    f32x4 sacc[4];
    for (int i = 0; i < 4; ++i) sacc[i] = zero;
    bf16x8 qf0 = *(const bf16x8*)(Qs + (w * 16 + l15) * 72 + l4 * 8);
    bf16x8 qf1 = *(const bf16x8*)(Qs + (w * 16 + l15) * 72 + 32 + l4 * 8);
#pragma unroll
    for (int nt = 0; nt < 4; ++nt) {
      bf16x8 kf0 = *(const bf16x8*)(Ks + (nt * 16 + l15) * 72 + l4 * 8);
      bf16x8 kf1 = *(const bf16x8*)(Ks + (nt * 16 + l15) * 72 + 32 + l4 * 8);
      sacc[nt] = __builtin_amdgcn_mfma_f32_16x16x32_bf16(qf0, kf0, sacc[nt], 0, 0, 0);
      sacc[nt] = __builtin_amdgcn_mfma_f32_16x16x32_bf16(qf1, kf1, sacc[nt], 0, 0, 0);
    }

    // mask + online softmax (C layout: row = l4*4+r, col = nt*16+l15)
    float mnew[4], al[4];
#pragma unroll
    for (int r = 0; r < 4; ++r) {
      int gqr = gq[w * 16 + l4 * 4 + r];
      float mx = -1e30f;
#pragma unroll
      for (int nt = 0; nt < 4; ++nt) {
        float sv = sacc[nt][r];
        if (gqr == gk[nt * 16 + l15]) sv = -1e9f;
        sacc[nt][r] = sv;
        mx = fmaxf(mx, sv);
      }
      for (int off = 1; off < 16; off <<= 1) mx = fmaxf(mx, __shfl_xor(mx, off, 64));
      mnew[r] = fmaxf(m[r], mx);
      al[r] = __expf(m[r] - mnew[r]);
      m[r] = mnew[r];
    }
    float rsum[4];
#pragma unroll
    for (int r = 0; r < 4; ++r) {
      float sm = 0.f;
#pragma unroll
      for (int nt = 0; nt < 4; ++nt) {
        float p = __expf(sacc[nt][r] - mnew[r]);
        sacc[nt][r] = p;
        sm += p;
      }
      for (int off = 1; off < 16; off <<= 1) sm += __shfl_xor(sm, off, 64);
      rsum[r] = sm;
    }
#pragma unroll
    for (int r = 0; r < 4; ++r) {
      l[r] = l[r] * al[r] + rsum[r];
#pragma unroll
      for (int nt = 0; nt < 4; ++nt) oacc[nt][r] = oacc[nt][r] * al[r];
    }
    // P to LDS (C layout -> A layout via LDS round trip)
#pragma unroll
    for (int r = 0; r < 4; ++r)
#pragma unroll
      for (int nt = 0; nt < 4; ++nt)
        Ps[(w * 16 + l4 * 4 + r) * 72 + nt * 16 + l15] = (bf16_t)sacc[nt][r];
    __syncthreads();
    // O += P V
    bf16x8 pf0 = *(const bf16x8*)(Ps + (w * 16 + l15) * 72 + l4 * 8);
    bf16x8 pf1 = *(const bf16x8*)(Ps + (w * 16 + l15) * 72 + 32 + l4 * 8);
#pragma unroll
    for (int nt = 0; nt < 4; ++nt) {
      bf16x8 vf0 = *(const bf16x8*)(Vs + (nt * 16 + l15) * 72 + l4 * 8);
      bf16x8 vf1 = *(const bf16x8*)(Vs + (nt * 16 + l15) * 72 + 32 + l4 * 8);
      oacc[nt] = __builtin_amdgcn_mfma_f32_16x16x32_bf16(pf0, vf0, oacc[nt], 0, 0, 0);
      oacc[nt] = __builtin_amdgcn_mfma_f32_16x16x32_bf16(pf1, vf1, oacc[nt], 0, 0, 0);
    }
  }
  // epilogue: normalize and store to attn_o (B,S,D) bf16
#pragma unroll
  for (int r = 0; r < 4; ++r) {
    float inv = 1.f / l[r];
    int srow = qBase + w * 16 + l4 * 4 + r;
#pragma unroll
    for (int nt = 0; nt < 4; ++nt)
      outp[((size_t)(b * 1024 + srow)) * 1024 + h * 64 + nt * 16 + l15] =
          (bf16_t)(oacc[nt][r] * inv);
  }
}

// ---------------------------------------------------------------------------
// m97-style GEMM: C[M,N] = A[M,Kd] @ Bt[N,Kd]^T, bf16 MFMA, 128x128 tile,
// BK=32, global_load_lds width-16 staging.  EPI: 0=bf16, 1=bias+gelu->bf16,
// 2=g_msa*v+resid gated ->f32, 3=g_mlp*(v+bias)+resid gated ->f32
// ---------------------------------------------------------------------------
__device__ __forceinline__ void stage16(const bf16_t* gp, bf16_t* lp) {
  __builtin_amdgcn_global_load_lds(
      (__attribute__((address_space(1))) void*)gp,
      (__attribute__((address_space(3))) void*)lp, 16, 0, 0);
}

template <int EPI>
__global__ __launch_bounds__(256, 2) void gemm_bt(
    const bf16_t* __restrict__ A, const bf16_t* __restrict__ Bt,
    int M, int N, int Kd,
    float* __restrict__ Cf, bf16_t* __restrict__ Cb,
    const float* __restrict__ bias,
    const float* __restrict__ mod, int gOff,
    const float* __restrict__ resid,
    const int* __restrict__ enabled)
{
  __shared__ bf16_t sA[128 * 32];
  __shared__ bf16_t sB[128 * 32];
  const int tid = threadIdx.x;
  const int lane = tid & 63, w = tid >> 6;
  const int wr = w >> 1, wc = w & 1;
  const int rowBase = blockIdx.y * 128;
  const int colBase = blockIdx.x * 128;
  const int l15 = lane & 15, l4 = lane >> 4;
  const int sr = lane >> 2, scc = (lane & 3) * 8;

  const f32x4 zero = {0.f, 0.f, 0.f, 0.f};
  f32x4 acc[4][4];
#pragma unroll
  for (int i = 0; i < 4; ++i)
#pragma unroll
    for (int j = 0; j < 4; ++j) acc[i][j] = zero;

  const bf16_t* aBase = A + (size_t)(rowBase + w * 32 + sr) * Kd + scc;
  const bf16_t* bBase = Bt + (size_t)(colBase + w * 32 + sr) * Kd + scc;

  for (int k0 = 0; k0 < Kd; k0 += 32) {
    __syncthreads();
#pragma unroll
    for (int i = 0; i < 2; ++i) {
      stage16(aBase + (size_t)i * 16 * Kd + k0, sA + (w * 32 + i * 16) * 32);
      stage16(bBase + (size_t)i * 16 * Kd + k0, sB + (w * 32 + i * 16) * 32);
    }
    __syncthreads();
    bf16x8 af[4], bfr[4];
#pragma unroll
    for (int mt = 0; mt < 4; ++mt)
      af[mt] = *(const bf16x8*)(sA + (wr * 64 + mt * 16 + l15) * 32 + l4 * 8);
#pragma unroll
    for (int nt = 0; nt < 4; ++nt)
      bfr[nt] = *(const bf16x8*)(sB + (wc * 64 + nt * 16 + l15) * 32 + l4 * 8);
#pragma unroll
    for (int mt = 0; mt < 4; ++mt)
#pragma unroll
      for (int nt = 0; nt < 4; ++nt)
        acc[mt][nt] = __builtin_amdgcn_mfma_f32_16x16x32_bf16(af[mt], bfr[nt],
                                                              acc[mt][nt], 0, 0, 0);
  }

#pragma unroll
  for (int mt = 0; mt < 4; ++mt) {
#pragma unroll
    for (int nt = 0; nt < 4; ++nt) {
      int col = colBase + wc * 64 + nt * 16 + l15;
#pragma unroll
      for (int r = 0; r < 4; ++r) {
        int rr = rowBase + wr * 64 + mt * 16 + l4 * 4 + r;
        float v = acc[mt][nt][r];
        if constexpr (EPI == 0) {
          Cb[(size_t)rr * N + col] = (bf16_t)v;
        } else if constexpr (EPI == 1) {
          float t = v + bias[col];
          float g = 0.5f * t *
                    (1.0f + tanhf(0.7978845608028654f * (t + 0.044715f * t * t * t)));
          Cb[(size_t)rr * N + col] = (bf16_t)g;
        } else if constexpr (EPI == 2) {
          int b = rr >> 10;
          float res = resid[(size_t)rr * N + col];
          float o = enabled[rr] ? (mod[b * 6144 + gOff + col] * v + res) : res;
          Cf[(size_t)rr * N + col] = o;
        } else {
          int b = rr >> 10;
          float h2 = v + bias[col];
          float xm = resid[(size_t)rr * N + col];
          float o = enabled[rr] ? (mod[b * 6144 + gOff + col] * h2 + xm) : xm;
          Cf[(size_t)rr * N + col] = o;
        }
      }
    }
  }
}

// ---------------------------------------------------------------------------
extern "C" void kernel_launch(void* const* d_in, const int* in_sizes, int n_in,
                              void* d_out, int out_size, void* d_ws, size_t ws_size,
                              hipStream_t stream)
{
  const float* q_x    = (const float*)d_in[0];
  const float* kv_x   = (const float*)d_in[1];
  const float* t_cond = (const float*)d_in[2];
  const float* cos_q  = (const float*)d_in[3];
  const float* sin_q  = (const float*)d_in[4];
  const float* cos_k  = (const float*)d_in[5];
  const float* sin_k  = (const float*)d_in[6];
  const int*   grp    = (const int*)d_in[7];
  const int*   qen    = (const int*)d_in[8];
  const float* qn_w   = (const float*)d_in[9];
  const float* kvn_w  = (const float*)d_in[10];
  const float* n2_w   = (const float*)d_in[11];
  const float* Wq     = (const float*)d_in[12];
  const float* Wkv    = (const float*)d_in[13];
  const float* Wo     = (const float*)d_in[14];
  const float* W1     = (const float*)d_in[15];
  const float* b1     = (const float*)d_in[16];
  const float* W2     = (const float*)d_in[17];
  const float* b2     = (const float*)d_in[18];
  const float* adaW   = (const float*)d_in[19];
  const float* adab   = (const float*)d_in[20];
  float* out = (float*)d_out;

  char* ws = (char*)d_ws;
  size_t off = 0;
  auto take = [&](size_t nbytes) -> void* {
    off = (off + 255) & ~(size_t)255;
    void* p = ws + off;
    off += nbytes;
    return p;
  };
  float*  mod    = (float*) take(4ull * 6144 * 4);
  bf16_t* Wq_t   = (bf16_t*)take(1024ull * 1024 * 2);
  bf16_t* Wkv_t  = (bf16_t*)take(2048ull * 1024 * 2);
  bf16_t* Wo_t   = (bf16_t*)take(1024ull * 1024 * 2);
  bf16_t* W1_t   = (bf16_t*)take(4096ull * 1024 * 2);
  bf16_t* W2_t   = (bf16_t*)take(1024ull * 4096 * 2);
  bf16_t* qn_mod = (bf16_t*)take(4096ull * 1024 * 2);
  bf16_t* kvn    = (bf16_t*)take(4096ull * 1024 * 2);
  bf16_t* qf     = (bf16_t*)take(4096ull * 1024 * 2);
  bf16_t* kvf    = (bf16_t*)take(4096ull * 2048 * 2);
  bf16_t* q_r    = (bf16_t*)take(4096ull * 1024 * 2);
  bf16_t* k_r    = (bf16_t*)take(4096ull * 1024 * 2);
  bf16_t* v_t    = (bf16_t*)take(4096ull * 1024 * 2);
  bf16_t* attn_o = (bf16_t*)take(4096ull * 1024 * 2);
  float*  xbuf   = (float*) take(4096ull * 1024 * 4);
  bf16_t* xn_mod = (bf16_t*)take(4096ull * 1024 * 2);
  bf16_t* h1     = (bf16_t*)take(4096ull * 4096 * 2);

  // 1. adaLN modulation
  mod_gemm_kernel<<<dim3(24), 256, 0, stream>>>(t_cond, adaW, adab, mod);
  // 2. weight prep (transpose + bf16)
  transpose_to_bf16<<<dim3(32, 32),  dim3(32, 8), 0, stream>>>(Wq,  Wq_t,  1024, 1024);
  transpose_to_bf16<<<dim3(64, 32),  dim3(32, 8), 0, stream>>>(Wkv, Wkv_t, 1024, 2048);
  transpose_to_bf16<<<dim3(32, 32),  dim3(32, 8), 0, stream>>>(Wo,  Wo_t,  1024, 1024);
  transpose_to_bf16<<<dim3(128, 32), dim3(32, 8), 0, stream>>>(W1,  W1_t,  1024, 4096);
  transpose_to_bf16<<<dim3(32, 128), dim3(32, 8), 0, stream>>>(W2,  W2_t,  4096, 1024);
  // 3. LayerNorms (+msa modulation for q side)
  ln_mod_kernel<<<4096, 256, 0, stream>>>(q_x,  qn_w,  mod, 1, 0, 1024, qn_mod);
  ln_mod_kernel<<<4096, 256, 0, stream>>>(kv_x, kvn_w, mod, 0, 0, 0,    kvn);
  // 4. QKV projections
  gemm_bt<0><<<dim3(8, 32),  256, 0, stream>>>(qn_mod, Wq_t,  4096, 1024, 1024,
      nullptr, qf,  nullptr, nullptr, 0, nullptr, nullptr);
  gemm_bt<0><<<dim3(16, 32), 256, 0, stream>>>(kvn,    Wkv_t, 4096, 2048, 1024,
      nullptr, kvf, nullptr, nullptr, 0, nullptr, nullptr);
  // 5. RoPE + relayout
  rope_q_kernel<<<16384, 256, 0, stream>>>(qf, cos_q, sin_q, q_r);
  rope_kv_kernel<<<16384, 256, 0, stream>>>(kvf, cos_k, sin_k, k_r, v_t);
  // 6. attention
  attn_kernel<<<dim3(64, 16), 256, 0, stream>>>(q_r, k_r, v_t, grp, attn_o);
  // 7. output proj + msa gate + residual + query gate -> x (f32)
  gemm_bt<2><<<dim3(8, 32), 256, 0, stream>>>(attn_o, Wo_t, 4096, 1024, 1024,
      xbuf, nullptr, nullptr, mod, 2048, q_x, qen);
  // 8. LN2 + mlp modulation
  ln_mod_kernel<<<4096, 256, 0, stream>>>(xbuf, n2_w, mod, 1, 3072, 4096, xn_mod);
  // 9. MLP up + gelu
  gemm_bt<1><<<dim3(32, 32), 256, 0, stream>>>(xn_mod, W1_t, 4096, 4096, 1024,
      nullptr, h1, b1, nullptr, 0, nullptr, nullptr);
  // 10. MLP down + mlp gate + residual + query gate -> d_out (f32)
  gemm_bt<3><<<dim3(8, 32), 256, 0, stream>>>(h1, W2_t, 4096, 1024, 4096,
      out, nullptr, b2, mod, 5120, xbuf, qen);
}

// Round 2
// 513.965 us; speedup vs baseline: 1.2049x; 1.2049x over previous
//
#include <hip/hip_runtime.h>
#include <hip/hip_bf16.h>
#include <math.h>

typedef __bf16 bf16_t;
typedef __attribute__((ext_vector_type(8))) __bf16 bf16x8;
typedef __attribute__((ext_vector_type(4))) float f32x4;

// ---------------------------------------------------------------------------
// mod init: mod[b][c] = adab[c]
// ---------------------------------------------------------------------------
__global__ __launch_bounds__(256) void mod_init_kernel(
    const float* __restrict__ adab, float* __restrict__ mod)
{
  int i = blockIdx.x * 256 + threadIdx.x;  // < 24576
  int b = i / 6144, c = i - b * 6144;
  mod[i] = adab[c];
  (void)b;
}

// ---------------------------------------------------------------------------
// mod partial: split-K over the 1024 reduction dim, atomicAdd into mod.
// grid (24, 8) x 256
// ---------------------------------------------------------------------------
__global__ __launch_bounds__(256) void mod_partial_kernel(
    const float* __restrict__ tc, const float* __restrict__ adaW,
    float* __restrict__ mod)
{
  __shared__ float st[4][128];
  int tid = threadIdx.x, z = blockIdx.y;
  for (int i = tid; i < 512; i += 256)
    st[i >> 7][i & 127] = tc[(i >> 7) * 1024 + z * 128 + (i & 127)];
  __syncthreads();
  int col = blockIdx.x * 256 + tid;
  float a0 = 0.f, a1 = 0.f, a2 = 0.f, a3 = 0.f;
  for (int k = 0; k < 128; ++k) {
    float wv = adaW[(size_t)(z * 128 + k) * 6144 + col];
    a0 = fmaf(st[0][k], wv, a0);
    a1 = fmaf(st[1][k], wv, a1);
    a2 = fmaf(st[2][k], wv, a2);
    a3 = fmaf(st[3][k], wv, a3);
  }
  atomicAdd(&mod[col], a0);
  atomicAdd(&mod[6144 + col], a1);
  atomicAdd(&mod[2 * 6144 + col], a2);
  atomicAdd(&mod[3 * 6144 + col], a3);
}

// ---------------------------------------------------------------------------
// Transposing f32 -> bf16 weight prep: out[c][r] = (bf16) in[r][c]
// ---------------------------------------------------------------------------
__global__ __launch_bounds__(256) void transpose_to_bf16(
    const float* __restrict__ in, bf16_t* __restrict__ out, int R, int C)
{
  __shared__ float tile[32][33];
  int c0 = blockIdx.x * 32, r0 = blockIdx.y * 32;
  int tx = threadIdx.x, ty = threadIdx.y;
#pragma unroll
  for (int i = 0; i < 4; ++i)
    tile[ty + i * 8][tx] = in[(size_t)(r0 + ty + i * 8) * C + c0 + tx];
  __syncthreads();
#pragma unroll
  for (int i = 0; i < 4; ++i)
    out[(size_t)(c0 + ty + i * 8) * R + r0 + tx] = (bf16_t)tile[tx][ty + i * 8];
}

// ---------------------------------------------------------------------------
// LayerNorm (+ optional adaLN shift/scale) -> bf16.  One block per row (D=1024).
// ---------------------------------------------------------------------------
__global__ __launch_bounds__(256) void ln_mod_kernel(
    const float* __restrict__ x, const float* __restrict__ wgt,
    const float* __restrict__ mod, int useMod, int shOff, int scOff,
    bf16_t* __restrict__ out)
{
  int row = blockIdx.x;
  int b = row >> 10;
  int tid = threadIdx.x;
  const float* xr = x + (size_t)row * 1024;
  float4 v = ((const float4*)xr)[tid];
  float s = v.x + v.y + v.z + v.w;
  float s2 = v.x * v.x + v.y * v.y + v.z * v.z + v.w * v.w;
#pragma unroll
  for (int off = 32; off > 0; off >>= 1) {
    s += __shfl_down(s, off, 64);
    s2 += __shfl_down(s2, off, 64);
  }
  __shared__ float ps[4], ps2[4];
  if ((tid & 63) == 0) { ps[tid >> 6] = s; ps2[tid >> 6] = s2; }
  __syncthreads();
  float mu = (ps[0] + ps[1] + ps[2] + ps[3]) * (1.0f / 1024.0f);
  float var = (ps2[0] + ps2[1] + ps2[2] + ps2[3]) * (1.0f / 1024.0f) - mu * mu;
  float rs = rsqrtf(var + 1e-5f);
  float xv[4] = {v.x, v.y, v.z, v.w};
#pragma unroll
  for (int i = 0; i < 4; ++i) {
    int col = tid * 4 + i;
    float n = (xv[i] - mu) * rs * wgt[col];
    if (useMod)
      n = n * (1.0f + mod[b * 6144 + scOff + col]) + mod[b * 6144 + shOff + col];
    out[(size_t)row * 1024 + col] = (bf16_t)n;
  }
}

// ---------------------------------------------------------------------------
// Reduce split-K partials of Q proj + RoPE + scale -> q_r (B,H,S,64) bf16
// ---------------------------------------------------------------------------
__global__ __launch_bounds__(256) void reduce_q_rope_kernel(
    const float* __restrict__ P0, const float* __restrict__ P1,
    const float* __restrict__ cosq, const float* __restrict__ sinq,
    bf16_t* __restrict__ qr)
{
  int t = blockIdx.x * 256 + threadIdx.x;  // < 2M
  int hd = t & 31;
  int h = (t >> 5) & 15;
  int s = (t >> 9) & 1023;
  int b = t >> 19;
  size_t base = ((size_t)(b * 1024 + s)) * 1024 + h * 64 + hd;
  float v1 = P0[base] + P1[base];
  float v2 = P0[base + 32] + P1[base + 32];
  float c1 = cosq[s * 64 + hd], s1 = sinq[s * 64 + hd];
  float c2 = cosq[s * 64 + hd + 32], s2 = sinq[s * 64 + hd + 32];
  float o1 = (v1 * c1 - v2 * s1) * 0.125f;
  float o2 = (v2 * c2 + v1 * s2) * 0.125f;
  size_t ob = ((size_t)(b * 16 + h) * 1024 + s) * 64 + hd;
  qr[ob] = (bf16_t)o1;
  qr[ob + 32] = (bf16_t)o2;
}

// ---------------------------------------------------------------------------
// Reduce split-K partials of KV proj: RoPE on K -> k_r (B,H,K,64);
// V transposed via LDS -> v_t (B,H,64,K).  grid (64 bh, 16 ntile) x 256
// ---------------------------------------------------------------------------
__global__ __launch_bounds__(256) void reduce_kv_kernel(
    const float* __restrict__ P0, const float* __restrict__ P1,
    const float* __restrict__ cosk, const float* __restrict__ sink,
    bf16_t* __restrict__ kr, bf16_t* __restrict__ vt)
{
  __shared__ float ks[64][65];
  __shared__ float vs[64][65];
  int bh = blockIdx.x;
  int b = bh >> 4, h = bh & 15;
  int n0 = blockIdx.y * 64;
  int tid = threadIdx.x;
#pragma unroll
  for (int it = 0; it < 16; ++it) {
    int linear = tid + it * 256;
    int nl = linear >> 6, hd = linear & 63;
    size_t gi = ((size_t)(b * 1024 + n0 + nl)) * 2048 + h * 64 + hd;
    ks[nl][hd] = P0[gi] + P1[gi];
    vs[hd][nl] = P0[gi + 1024] + P1[gi + 1024];
  }
  __syncthreads();
#pragma unroll
  for (int it = 0; it < 16; ++it) {
    int linear = tid + it * 256;
    int nl = linear >> 6, hd = linear & 63;
    float kv = ks[nl][hd];
    float pv = ks[nl][hd ^ 32];
    float c = cosk[(n0 + nl) * 64 + hd], sn = sink[(n0 + nl) * 64 + hd];
    float o = (hd < 32) ? (kv * c - pv * sn) : (kv * c + pv * sn);
    kr[((size_t)bh * 1024 + n0 + nl) * 64 + hd] = (bf16_t)o;
    int rh = linear >> 6, nn = linear & 63;  // reuse for v store
    vt[((size_t)bh * 64 + rh) * 1024 + n0 + nn] = (bf16_t)vs[rh][nn];
  }
}

// ---------------------------------------------------------------------------
// Flash-style attention with group mask.  One block per (b,h, 64-row Q tile).
// ---------------------------------------------------------------------------
__global__ __launch_bounds__(256, 2) void attn_kernel(
    const bf16_t* __restrict__ qr, const bf16_t* __restrict__ kr,
    const bf16_t* __restrict__ vt, const int* __restrict__ grp,
    bf16_t* __restrict__ outp)
{
  __shared__ bf16_t Qs[64 * 72];
  __shared__ bf16_t Ks[64 * 72];
  __shared__ bf16_t Vs[64 * 72];
  __shared__ bf16_t Ps[64 * 72];
  __shared__ int gq[64], gk[64];
  const int bh = blockIdx.x;
  const int b = bh >> 4;
  const int qBase = blockIdx.y * 64;
  const int tid = threadIdx.x, lane = tid & 63, w = tid >> 6;
  const int l15 = lane & 15, l4 = lane >> 4;
  const f32x4 zero = {0.f, 0.f, 0.f, 0.f};

#pragma unroll
  for (int i = 0; i < 2; ++i) {
    int c = tid * 2 + i;
    int r = c >> 3, cc = (c & 7) * 8;
    *(bf16x8*)(Qs + r * 72 + cc) =
        *(const bf16x8*)(qr + (((size_t)bh) * 1024 + qBase + r) * 64 + cc);
  }
  if (tid < 64) gq[tid] = grp[b * 1024 + qBase + tid];

  f32x4 oacc[4];
  for (int i = 0; i < 4; ++i) oacc[i] = zero;
  float m[4], l[4];
  for (int r = 0; r < 4; ++r) { m[r] = -1e30f; l[r] = 0.f; }

  for (int kt = 0; kt < 16; ++kt) {
    __syncthreads();
#pragma unroll
    for (int i = 0; i < 2; ++i) {
      int c = tid * 2 + i;
      int r = c >> 3, cc = (c & 7) * 8;
      *(bf16x8*)(Ks + r * 72 + cc) =
          *(const bf16x8*)(kr + ((size_t)bh * 1024 + kt * 64 + r) * 64 + cc);
      *(bf16x8*)(Vs + r * 72 + cc) =
          *(const bf16x8*)(vt + ((size_t)bh * 64 + r) * 1024 + kt * 64 + cc);
    }
    if (tid < 64) gk[tid] = grp[b * 1024 + kt * 64 + tid];
    __syncthreads();

    f32x4 sacc[4];
    for (int i = 0; i < 4; ++i) sacc[i] = zero;
    bf16x8 qf0 = *(const bf16x8*)(Qs + (w * 16 + l15) * 72 + l4 * 8);
    bf16x8 qf1 = *(const bf16x8*)(Qs + (w * 16 + l15) * 72 + 32 + l4 * 8);
#pragma unroll
    for (int nt = 0; nt < 4; ++nt) {
      bf16x8 kf0 = *(const bf16x8*)(Ks + (nt * 16 + l15) * 72 + l4 * 8);
      bf16x8 kf1 = *(const bf16x8*)(Ks + (nt * 16 + l15) * 72 + 32 + l4 * 8);
      sacc[nt] = __builtin_amdgcn_mfma_f32_16x16x32_bf16(qf0, kf0, sacc[nt], 0, 0, 0);
      sacc[nt] = __builtin_amdgcn_mfma_f32_16x16x32_bf16(qf1, kf1, sacc[nt], 0, 0, 0);
    }

    float mnew[4], al[4];
#pragma unroll
    for (int r = 0; r < 4; ++r) {
      int gqr = gq[w * 16 + l4 * 4 + r];
      float mx = -1e30f;
#pragma unroll
      for (int nt = 0; nt < 4; ++nt) {
        float sv = sacc[nt][r];
        if (gqr == gk[nt * 16 + l15]) sv = -1e9f;
        sacc[nt][r] = sv;
        mx = fmaxf(mx, sv);
      }
      for (int off = 1; off < 16; off <<= 1) mx = fmaxf(mx, __shfl_xor(mx, off, 64));
      mnew[r] = fmaxf(m[r], mx);
      al[r] = __expf(m[r] - mnew[r]);
      m[r] = mnew[r];
    }
    float rsum[4];
#pragma unroll
    for (int r = 0; r < 4; ++r) {
      float sm = 0.f;
#pragma unroll
      for (int nt = 0; nt < 4; ++nt) {
        float p = __expf(sacc[nt][r] - mnew[r]);
        sacc[nt][r] = p;
        sm += p;
      }
      for (int off = 1; off < 16; off <<= 1) sm += __shfl_xor(sm, off, 64);
      rsum[r] = sm;
    }
#pragma unroll
    for (int r = 0; r < 4; ++r) {
      l[r] = l[r] * al[r] + rsum[r];
#pragma unroll
      for (int nt = 0; nt < 4; ++nt) oacc[nt][r] = oacc[nt][r] * al[r];
    }
#pragma unroll
    for (int r = 0; r < 4; ++r)
#pragma unroll
      for (int nt = 0; nt < 4; ++nt)
        Ps[(w * 16 + l4 * 4 + r) * 72 + nt * 16 + l15] = (bf16_t)sacc[nt][r];
    __syncthreads();
    bf16x8 pf0 = *(const bf16x8*)(Ps + (w * 16 + l15) * 72 + l4 * 8);
    bf16x8 pf1 = *(const bf16x8*)(Ps + (w * 16 + l15) * 72 + 32 + l4 * 8);
#pragma unroll
    for (int nt = 0; nt < 4; ++nt) {
      bf16x8 vf0 = *(const bf16x8*)(Vs + (nt * 16 + l15) * 72 + l4 * 8);
      bf16x8 vf1 = *(const bf16x8*)(Vs + (nt * 16 + l15) * 72 + 32 + l4 * 8);
      oacc[nt] = __builtin_amdgcn_mfma_f32_16x16x32_bf16(pf0, vf0, oacc[nt], 0, 0, 0);
      oacc[nt] = __builtin_amdgcn_mfma_f32_16x16x32_bf16(pf1, vf1, oacc[nt], 0, 0, 0);
    }
  }
#pragma unroll
  for (int r = 0; r < 4; ++r) {
    float inv = 1.f / l[r];
    int srow = qBase + w * 16 + l4 * 4 + r;
#pragma unroll
    for (int nt = 0; nt < 4; ++nt)
      outp[((size_t)(b * 1024 + srow)) * 1024 + (bh & 15) * 64 + nt * 16 + l15] =
          (bf16_t)(oacc[nt][r] * inv);
  }
}

// ---------------------------------------------------------------------------
// m97-style GEMM with split-K (blockIdx.z) and XOR-swizzled LDS.
// EPI: 1 = bias+gelu->bf16,  4 = f32 partial to Cf + z*M*N
// ---------------------------------------------------------------------------
__device__ __forceinline__ void stage16(const bf16_t* gp, bf16_t* lp) {
  __builtin_amdgcn_global_load_lds(
      (__attribute__((address_space(1))) void*)gp,
      (__attribute__((address_space(3))) void*)lp, 16, 0, 0);
}

template <int EPI>
__global__ __launch_bounds__(256, 2) void gemm_bt(
    const bf16_t* __restrict__ A, const bf16_t* __restrict__ Bt,
    int M, int N, int Kd, int kChunk,
    float* __restrict__ Cf, bf16_t* __restrict__ Cb,
    const float* __restrict__ bias)
{
  __shared__ bf16_t sA[128 * 32];
  __shared__ bf16_t sB[128 * 32];
  const int tid = threadIdx.x;
  const int lane = tid & 63, w = tid >> 6;
  const int wr = w >> 1, wc = w & 1;
  const int rowBase = blockIdx.y * 128;
  const int colBase = blockIdx.x * 128;
  const int l15 = lane & 15, l4 = lane >> 4;
  const int sr = lane >> 2;
  const int scc = (((lane & 3) ^ ((sr >> 1) & 3))) * 8;  // XOR-swizzled granule
  const int l4s = l4 ^ ((l15 >> 1) & 3);                 // matching read swizzle

  const f32x4 zero = {0.f, 0.f, 0.f, 0.f};
  f32x4 acc[4][4];
#pragma unroll
  for (int i = 0; i < 4; ++i)
#pragma unroll
    for (int j = 0; j < 4; ++j) acc[i][j] = zero;

  const bf16_t* aBase = A + (size_t)(rowBase + w * 32 + sr) * Kd + scc;
  const bf16_t* bBase = Bt + (size_t)(colBase + w * 32 + sr) * Kd + scc;

  const int kStart = blockIdx.z * kChunk;
  for (int k0 = kStart; k0 < kStart + kChunk; k0 += 32) {
    __syncthreads();
#pragma unroll
    for (int i = 0; i < 2; ++i) {
      stage16(aBase + (size_t)i * 16 * Kd + k0, sA + (w * 32 + i * 16) * 32);
      stage16(bBase + (size_t)i * 16 * Kd + k0, sB + (w * 32 + i * 16) * 32);
    }
    __syncthreads();
    bf16x8 af[4], bfr[4];
#pragma unroll
    for (int mt = 0; mt < 4; ++mt)
      af[mt] = *(const bf16x8*)(sA + (wr * 64 + mt * 16 + l15) * 32 + l4s * 8);
#pragma unroll
    for (int nt = 0; nt < 4; ++nt)
      bfr[nt] = *(const bf16x8*)(sB + (wc * 64 + nt * 16 + l15) * 32 + l4s * 8);
#pragma unroll
    for (int mt = 0; mt < 4; ++mt)
#pragma unroll
      for (int nt = 0; nt < 4; ++nt)
        acc[mt][nt] = __builtin_amdgcn_mfma_f32_16x16x32_bf16(af[mt], bfr[nt],
                                                              acc[mt][nt], 0, 0, 0);
  }

  const size_t zOff = (size_t)blockIdx.z * M * N;
#pragma unroll
  for (int mt = 0; mt < 4; ++mt) {
#pragma unroll
    for (int nt = 0; nt < 4; ++nt) {
      int col = colBase + wc * 64 + nt * 16 + l15;
#pragma unroll
      for (int r = 0; r < 4; ++r) {
        int rr = rowBase + wr * 64 + mt * 16 + l4 * 4 + r;
        float v = acc[mt][nt][r];
        if constexpr (EPI == 1) {
          float t = v + bias[col];
          float g = 0.5f * t *
                    (1.0f + tanhf(0.7978845608028654f * (t + 0.044715f * t * t * t)));
          Cb[(size_t)rr * N + col] = (bf16_t)g;
        } else {
          Cf[zOff + (size_t)rr * N + col] = v;
        }
      }
    }
  }
}

// ---------------------------------------------------------------------------
// Fused: Wo split-K reduce + msa gate + residual + query gate -> xbuf (f32),
// then LN2 + mlp modulation -> xn_mod (bf16).  One block per row.
// ---------------------------------------------------------------------------
__global__ __launch_bounds__(256) void ln2_fused_kernel(
    const float* __restrict__ P0, const float* __restrict__ P1,
    const float* __restrict__ qx, const float* __restrict__ n2w,
    const float* __restrict__ mod, const int* __restrict__ qen,
    float* __restrict__ xbuf, bf16_t* __restrict__ xnmod)
{
  int row = blockIdx.x;
  int b = row >> 10;
  int tid = threadIdx.x;
  bool en = qen[row] != 0;
  float4 p0 = ((const float4*)(P0 + (size_t)row * 1024))[tid];
  float4 p1 = ((const float4*)(P1 + (size_t)row * 1024))[tid];
  float4 res = ((const float4*)(qx + (size_t)row * 1024))[tid];
  float4 g = ((const float4*)(mod + b * 6144 + 2048))[tid];
  float4 x;
  x.x = en ? fmaf(g.x, p0.x + p1.x, res.x) : res.x;
  x.y = en ? fmaf(g.y, p0.y + p1.y, res.y) : res.y;
  x.z = en ? fmaf(g.z, p0.z + p1.z, res.z) : res.z;
  x.w = en ? fmaf(g.w, p0.w + p1.w, res.w) : res.w;
  ((float4*)(xbuf + (size_t)row * 1024))[tid] = x;

  float s = x.x + x.y + x.z + x.w;
  float s2 = x.x * x.x + x.y * x.y + x.z * x.z + x.w * x.w;
#pragma unroll
  for (int off = 32; off > 0; off >>= 1) {
    s += __shfl_down(s, off, 64);
    s2 += __shfl_down(s2, off, 64);
  }
  __shared__ float ps[4], ps2[4];
  if ((tid & 63) == 0) { ps[tid >> 6] = s; ps2[tid >> 6] = s2; }
  __syncthreads();
  float mu = (ps[0] + ps[1] + ps[2] + ps[3]) * (1.0f / 1024.0f);
  float var = (ps2[0] + ps2[1] + ps2[2] + ps2[3]) * (1.0f / 1024.0f) - mu * mu;
  float rs = rsqrtf(var + 1e-5f);
  float4 sc = ((const float4*)(mod + b * 6144 + 4096))[tid];
  float4 sh = ((const float4*)(mod + b * 6144 + 3072))[tid];
  float4 wv = ((const float4*)n2w)[tid];
  float xv[4] = {x.x, x.y, x.z, x.w};
  float scv[4] = {sc.x, sc.y, sc.z, sc.w};
  float shv[4] = {sh.x, sh.y, sh.z, sh.w};
  float wvv[4] = {wv.x, wv.y, wv.z, wv.w};
#pragma unroll
  for (int i = 0; i < 4; ++i) {
    float n = (xv[i] - mu) * rs * wvv[i];
    n = n * (1.0f + scv[i]) + shv[i];
    xnmod[(size_t)row * 1024 + tid * 4 + i] = (bf16_t)n;
  }
}

// ---------------------------------------------------------------------------
// Final: W2 split-4 reduce + bias + mlp gate + residual + query gate -> out f32
// ---------------------------------------------------------------------------
__global__ __launch_bounds__(256) void final_reduce_kernel(
    const float* __restrict__ P, const float* __restrict__ b2,
    const float* __restrict__ mod, const int* __restrict__ qen,
    const float* __restrict__ xbuf, float* __restrict__ out)
{
  int row = blockIdx.x;
  int b = row >> 10;
  int tid = threadIdx.x;
  bool en = qen[row] != 0;
  size_t ro = (size_t)row * 1024;
  float4 p0 = ((const float4*)(P + ro))[tid];
  float4 p1 = ((const float4*)(P + 4194304 + ro))[tid];
  float4 p2 = ((const float4*)(P + 2 * 4194304 + ro))[tid];
  float4 p3 = ((const float4*)(P + 3 * 4194304 + ro))[tid];
  float4 bb = ((const float4*)b2)[tid];
  float4 xm = ((const float4*)(xbuf + ro))[tid];
  float4 g = ((const float4*)(mod + b * 6144 + 5120))[tid];
  float4 o;
  o.x = en ? fmaf(g.x, p0.x + p1.x + p2.x + p3.x + bb.x, xm.x) : xm.x;
  o.y = en ? fmaf(g.y, p0.y + p1.y + p2.y + p3.y + bb.y, xm.y) : xm.y;
  o.z = en ? fmaf(g.z, p0.z + p1.z + p2.z + p3.z + bb.z, xm.z) : xm.z;
  o.w = en ? fmaf(g.w, p0.w + p1.w + p2.w + p3.w + bb.w, xm.w) : xm.w;
  ((float4*)(out + ro))[tid] = o;
}

// ---------------------------------------------------------------------------
extern "C" void kernel_launch(void* const* d_in, const int* in_sizes, int n_in,
                              void* d_out, int out_size, void* d_ws, size_t ws_size,
                              hipStream_t stream)
{
  const float* q_x    = (const float*)d_in[0];
  const float* kv_x   = (const float*)d_in[1];
  const float* t_cond = (const float*)d_in[2];
  const float* cos_q  = (const float*)d_in[3];
  const float* sin_q  = (const float*)d_in[4];
  const float* cos_k  = (const float*)d_in[5];
  const float* sin_k  = (const float*)d_in[6];
  const int*   grp    = (const int*)d_in[7];
  const int*   qen    = (const int*)d_in[8];
  const float* qn_w   = (const float*)d_in[9];
  const float* kvn_w  = (const float*)d_in[10];
  const float* n2_w   = (const float*)d_in[11];
  const float* Wq     = (const float*)d_in[12];
  const float* Wkv    = (const float*)d_in[13];
  const float* Wo     = (const float*)d_in[14];
  const float* W1     = (const float*)d_in[15];
  const float* b1     = (const float*)d_in[16];
  const float* W2     = (const float*)d_in[17];
  const float* b2     = (const float*)d_in[18];
  const float* adaW   = (const float*)d_in[19];
  const float* adab   = (const float*)d_in[20];
  float* out = (float*)d_out;

  char* ws = (char*)d_ws;
  const size_t MB = 1ull << 20;
  // layout (with deliberate aliasing; see lifetimes in comments)
  float*  mod    = (float*)(ws + 0);                  // 96 KB, whole call
  bf16_t* Wq_t   = (bf16_t*)(ws + 98304);             // 2 MB
  bf16_t* Wkv_t  = (bf16_t*)(ws + 98304 + 2 * MB);    // 4 MB
  bf16_t* Wo_t   = (bf16_t*)(ws + 98304 + 6 * MB);    // 2 MB
  bf16_t* W1_t   = (bf16_t*)(ws + 98304 + 8 * MB);    // 8 MB
  bf16_t* W2_t   = (bf16_t*)(ws + 98304 + 16 * MB);   // 8 MB
  bf16_t* qn_mod = (bf16_t*)(ws + 98304 + 24 * MB);   // 8 MB; reused as xn_mod
  bf16_t* kvn    = (bf16_t*)(ws + 98304 + 32 * MB);   // 8 MB; reused as attn_o
  bf16_t* q_r    = (bf16_t*)(ws + 98304 + 40 * MB);   // 8 MB; [q_r,k_r] reused as xbuf
  bf16_t* k_r    = (bf16_t*)(ws + 98304 + 48 * MB);   // 8 MB
  bf16_t* v_t    = (bf16_t*)(ws + 98304 + 56 * MB);   // 8 MB
  bf16_t* h1     = (bf16_t*)(ws + 98304 + 64 * MB);   // 32 MB
  float*  scr    = (float*)(ws + 98304 + 96 * MB);    // 64 MB split-K partials
  bf16_t* xn_mod = qn_mod;
  bf16_t* attn_o = kvn;
  float*  xbuf   = (float*)q_r;

  // 1. adaLN modulation (split-K + atomics)
  mod_init_kernel<<<96, 256, 0, stream>>>(adab, mod);
  mod_partial_kernel<<<dim3(24, 8), 256, 0, stream>>>(t_cond, adaW, mod);
  // 2. weight prep (transpose + bf16)
  transpose_to_bf16<<<dim3(32, 32),  dim3(32, 8), 0, stream>>>(Wq,  Wq_t,  1024, 1024);
  transpose_to_bf16<<<dim3(64, 32),  dim3(32, 8), 0, stream>>>(Wkv, Wkv_t, 1024, 2048);
  transpose_to_bf16<<<dim3(32, 32),  dim3(32, 8), 0, stream>>>(Wo,  Wo_t,  1024, 1024);
  transpose_to_bf16<<<dim3(128, 32), dim3(32, 8), 0, stream>>>(W1,  W1_t,  1024, 4096);
  transpose_to_bf16<<<dim3(32, 128), dim3(32, 8), 0, stream>>>(W2,  W2_t,  4096, 1024);
  // 3. LayerNorms
  ln_mod_kernel<<<4096, 256, 0, stream>>>(q_x,  qn_w,  mod, 1, 0, 1024, qn_mod);
  ln_mod_kernel<<<4096, 256, 0, stream>>>(kv_x, kvn_w, mod, 0, 0, 0,    kvn);
  // 4. Q proj (split-2) + reduce/RoPE
  gemm_bt<4><<<dim3(8, 32, 2), 256, 0, stream>>>(qn_mod, Wq_t, 4096, 1024, 1024, 512,
                                                 scr, nullptr, nullptr);
  reduce_q_rope_kernel<<<8192, 256, 0, stream>>>(scr, scr + 4194304, cos_q, sin_q, q_r);
  // 5. KV proj (split-2) + reduce/RoPE/V-transpose
  gemm_bt<4><<<dim3(16, 32, 2), 256, 0, stream>>>(kvn, Wkv_t, 4096, 2048, 1024, 512,
                                                  scr, nullptr, nullptr);
  reduce_kv_kernel<<<dim3(64, 16), 256, 0, stream>>>(scr, scr + 8388608, cos_k, sin_k,
                                                     k_r, v_t);
  // 6. attention
  attn_kernel<<<dim3(64, 16), 256, 0, stream>>>(q_r, k_r, v_t, grp, attn_o);
  // 7. output proj (split-2) + fused reduce/gate/residual/LN2
  gemm_bt<4><<<dim3(8, 32, 2), 256, 0, stream>>>(attn_o, Wo_t, 4096, 1024, 1024, 512,
                                                 scr, nullptr, nullptr);
  ln2_fused_kernel<<<4096, 256, 0, stream>>>(scr, scr + 4194304, q_x, n2_w, mod, qen,
                                             xbuf, xn_mod);
  // 8. MLP up + gelu
  gemm_bt<1><<<dim3(32, 32, 1), 256, 0, stream>>>(xn_mod, W1_t, 4096, 4096, 1024, 1024,
                                                  nullptr, h1, b1);
  // 9. MLP down (split-4) + final fused reduce -> out
  gemm_bt<4><<<dim3(8, 32, 4), 256, 0, stream>>>(h1, W2_t, 4096, 1024, 4096, 1024,
                                                 scr, nullptr, nullptr);
  final_reduce_kernel<<<4096, 256, 0, stream>>>(scr, b2, mod, qen, xbuf, out);
}

// Round 3
// 484.010 us; speedup vs baseline: 1.2795x; 1.0619x over previous
//
#include <hip/hip_runtime.h>
#include <hip/hip_bf16.h>
#include <math.h>

typedef __bf16 bf16_t;
typedef __attribute__((ext_vector_type(8))) __bf16 bf16x8;
typedef __attribute__((ext_vector_type(4))) float f32x4;

// ---------------------------------------------------------------------------
// mod init: mod[b][c] = adab[c]
// ---------------------------------------------------------------------------
__global__ __launch_bounds__(256) void mod_init_kernel(
    const float* __restrict__ adab, float* __restrict__ mod)
{
  int i = blockIdx.x * 256 + threadIdx.x;  // < 24576
  int b = i / 6144, c = i - b * 6144;
  mod[i] = adab[c];
  (void)b;
}

// ---------------------------------------------------------------------------
// mod partial: split-K over the 1024 reduction dim, atomicAdd into mod.
// grid (24, 8) x 256
// ---------------------------------------------------------------------------
__global__ __launch_bounds__(256) void mod_partial_kernel(
    const float* __restrict__ tc, const float* __restrict__ adaW,
    float* __restrict__ mod)
{
  __shared__ float st[4][128];
  int tid = threadIdx.x, z = blockIdx.y;
  for (int i = tid; i < 512; i += 256)
    st[i >> 7][i & 127] = tc[(i >> 7) * 1024 + z * 128 + (i & 127)];
  __syncthreads();
  int col = blockIdx.x * 256 + tid;
  float a0 = 0.f, a1 = 0.f, a2 = 0.f, a3 = 0.f;
  for (int k = 0; k < 128; ++k) {
    float wv = adaW[(size_t)(z * 128 + k) * 6144 + col];
    a0 = fmaf(st[0][k], wv, a0);
    a1 = fmaf(st[1][k], wv, a1);
    a2 = fmaf(st[2][k], wv, a2);
    a3 = fmaf(st[3][k], wv, a3);
  }
  atomicAdd(&mod[col], a0);
  atomicAdd(&mod[6144 + col], a1);
  atomicAdd(&mod[2 * 6144 + col], a2);
  atomicAdd(&mod[3 * 6144 + col], a3);
}

// ---------------------------------------------------------------------------
// Transposing f32 -> bf16 weight prep: out[c][r] = (bf16) in[r][c]
// ---------------------------------------------------------------------------
__global__ __launch_bounds__(256) void transpose_to_bf16(
    const float* __restrict__ in, bf16_t* __restrict__ out, int R, int C)
{
  __shared__ float tile[32][33];
  int c0 = blockIdx.x * 32, r0 = blockIdx.y * 32;
  int tx = threadIdx.x, ty = threadIdx.y;
#pragma unroll
  for (int i = 0; i < 4; ++i)
    tile[ty + i * 8][tx] = in[(size_t)(r0 + ty + i * 8) * C + c0 + tx];
  __syncthreads();
#pragma unroll
  for (int i = 0; i < 4; ++i)
    out[(size_t)(c0 + ty + i * 8) * R + r0 + tx] = (bf16_t)tile[tx][ty + i * 8];
}

// ---------------------------------------------------------------------------
// LayerNorm (+ optional adaLN shift/scale) -> bf16.  One block per row (D=1024).
// ---------------------------------------------------------------------------
__global__ __launch_bounds__(256) void ln_mod_kernel(
    const float* __restrict__ x, const float* __restrict__ wgt,
    const float* __restrict__ mod, int useMod, int shOff, int scOff,
    bf16_t* __restrict__ out)
{
  int row = blockIdx.x;
  int b = row >> 10;
  int tid = threadIdx.x;
  const float* xr = x + (size_t)row * 1024;
  float4 v = ((const float4*)xr)[tid];
  float s = v.x + v.y + v.z + v.w;
  float s2 = v.x * v.x + v.y * v.y + v.z * v.z + v.w * v.w;
#pragma unroll
  for (int off = 32; off > 0; off >>= 1) {
    s += __shfl_down(s, off, 64);
    s2 += __shfl_down(s2, off, 64);
  }
  __shared__ float ps[4], ps2[4];
  if ((tid & 63) == 0) { ps[tid >> 6] = s; ps2[tid >> 6] = s2; }
  __syncthreads();
  float mu = (ps[0] + ps[1] + ps[2] + ps[3]) * (1.0f / 1024.0f);
  float var = (ps2[0] + ps2[1] + ps2[2] + ps2[3]) * (1.0f / 1024.0f) - mu * mu;
  float rs = rsqrtf(var + 1e-5f);
  float xv[4] = {v.x, v.y, v.z, v.w};
#pragma unroll
  for (int i = 0; i < 4; ++i) {
    int col = tid * 4 + i;
    float n = (xv[i] - mu) * rs * wgt[col];
    if (useMod)
      n = n * (1.0f + mod[b * 6144 + scOff + col]) + mod[b * 6144 + shOff + col];
    out[(size_t)row * 1024 + col] = (bf16_t)n;
  }
}

// ---------------------------------------------------------------------------
// Reduce split-K partials of Q proj + RoPE + scale -> q_r (B,H,S,64) bf16
// ---------------------------------------------------------------------------
__global__ __launch_bounds__(256) void reduce_q_rope_kernel(
    const float* __restrict__ P0, const float* __restrict__ P1,
    const float* __restrict__ cosq, const float* __restrict__ sinq,
    bf16_t* __restrict__ qr)
{
  int t = blockIdx.x * 256 + threadIdx.x;  // < 2M
  int hd = t & 31;
  int h = (t >> 5) & 15;
  int s = (t >> 9) & 1023;
  int b = t >> 19;
  size_t base = ((size_t)(b * 1024 + s)) * 1024 + h * 64 + hd;
  float v1 = P0[base] + P1[base];
  float v2 = P0[base + 32] + P1[base + 32];
  float c1 = cosq[s * 64 + hd], s1 = sinq[s * 64 + hd];
  float c2 = cosq[s * 64 + hd + 32], s2 = sinq[s * 64 + hd + 32];
  float o1 = (v1 * c1 - v2 * s1) * 0.125f;
  float o2 = (v2 * c2 + v1 * s2) * 0.125f;
  size_t ob = ((size_t)(b * 16 + h) * 1024 + s) * 64 + hd;
  qr[ob] = (bf16_t)o1;
  qr[ob + 32] = (bf16_t)o2;
}

// ---------------------------------------------------------------------------
// Reduce split-K partials of KV proj: RoPE on K -> k_r (B,H,K,64);
// V transposed via LDS -> v_t (B,H,64,K).  grid (64 bh, 16 ntile) x 256
// ---------------------------------------------------------------------------
__global__ __launch_bounds__(256) void reduce_kv_kernel(
    const float* __restrict__ P0, const float* __restrict__ P1,
    const float* __restrict__ cosk, const float* __restrict__ sink,
    bf16_t* __restrict__ kr, bf16_t* __restrict__ vt)
{
  __shared__ float ks[64][65];
  __shared__ float vs[64][65];
  int bh = blockIdx.x;
  int b = bh >> 4, h = bh & 15;
  int n0 = blockIdx.y * 64;
  int tid = threadIdx.x;
#pragma unroll
  for (int it = 0; it < 16; ++it) {
    int linear = tid + it * 256;
    int nl = linear >> 6, hd = linear & 63;
    size_t gi = ((size_t)(b * 1024 + n0 + nl)) * 2048 + h * 64 + hd;
    ks[nl][hd] = P0[gi] + P1[gi];
    vs[hd][nl] = P0[gi + 1024] + P1[gi + 1024];
  }
  __syncthreads();
#pragma unroll
  for (int it = 0; it < 16; ++it) {
    int linear = tid + it * 256;
    int nl = linear >> 6, hd = linear & 63;
    float kv = ks[nl][hd];
    float pv = ks[nl][hd ^ 32];
    float c = cosk[(n0 + nl) * 64 + hd], sn = sink[(n0 + nl) * 64 + hd];
    float o = (hd < 32) ? (kv * c - pv * sn) : (kv * c + pv * sn);
    kr[((size_t)bh * 1024 + n0 + nl) * 64 + hd] = (bf16_t)o;
    int rh = linear >> 6, nn = linear & 63;  // reuse for v store
    vt[((size_t)bh * 64 + rh) * 1024 + n0 + nn] = (bf16_t)vs[rh][nn];
  }
}

// ---------------------------------------------------------------------------
// Flash-style attention, NO online softmax (scores are O(1); softmax is
// shift-invariant, so accumulate exp(s) directly, normalize once at the end).
// 128-row Q tile per block; wave w owns rows [32w,32w+32) as 2 strips of 16.
// Q fragments + q-groups live in registers; K/V staged per 64-col tile.
// ---------------------------------------------------------------------------
__global__ __launch_bounds__(256, 2) void attn_kernel(
    const bf16_t* __restrict__ qr, const bf16_t* __restrict__ kr,
    const bf16_t* __restrict__ vt, const int* __restrict__ grp,
    bf16_t* __restrict__ outp)
{
  __shared__ bf16_t Ks[64 * 72];
  __shared__ bf16_t Vs[64 * 72];
  __shared__ bf16_t Ps[128 * 72];
  __shared__ int gk[64];
  const int bh = blockIdx.x;
  const int b = bh >> 4, h = bh & 15;
  const int qBase = blockIdx.y * 128;
  const int tid = threadIdx.x, lane = tid & 63, w = tid >> 6;
  const int l15 = lane & 15, l4 = lane >> 4;
  const f32x4 zero = {0.f, 0.f, 0.f, 0.f};

  // Q fragments + q groups in registers
  bf16x8 qA0[2], qA1[2];
  int gqr[2][4];
#pragma unroll
  for (int s = 0; s < 2; ++s) {
    int row = qBase + w * 32 + s * 16;
    const bf16_t* qp = qr + ((size_t)bh * 1024 + row + l15) * 64;
    qA0[s] = *(const bf16x8*)(qp + l4 * 8);
    qA1[s] = *(const bf16x8*)(qp + 32 + l4 * 8);
#pragma unroll
    for (int r = 0; r < 4; ++r) gqr[s][r] = grp[b * 1024 + row + l4 * 4 + r];
  }

  f32x4 oacc[2][4];
  float rsum[2][4];
#pragma unroll
  for (int s = 0; s < 2; ++s)
#pragma unroll
    for (int i = 0; i < 4; ++i) { oacc[s][i] = zero; rsum[s][i] = 0.f; }

  for (int kt = 0; kt < 16; ++kt) {
    __syncthreads();
#pragma unroll
    for (int i = 0; i < 2; ++i) {
      int c = tid * 2 + i;
      int r = c >> 3, cc = (c & 7) * 8;
      *(bf16x8*)(Ks + r * 72 + cc) =
          *(const bf16x8*)(kr + ((size_t)bh * 1024 + kt * 64 + r) * 64 + cc);
      *(bf16x8*)(Vs + r * 72 + cc) =
          *(const bf16x8*)(vt + ((size_t)bh * 64 + r) * 1024 + kt * 64 + cc);
    }
    if (tid < 64) gk[tid] = grp[b * 1024 + kt * 64 + tid];
    __syncthreads();

    int gkv[4];
    bf16x8 kf0[4], kf1[4];
#pragma unroll
    for (int nt = 0; nt < 4; ++nt) {
      gkv[nt] = gk[nt * 16 + l15];
      kf0[nt] = *(const bf16x8*)(Ks + (nt * 16 + l15) * 72 + l4 * 8);
      kf1[nt] = *(const bf16x8*)(Ks + (nt * 16 + l15) * 72 + 32 + l4 * 8);
    }

#pragma unroll
    for (int s = 0; s < 2; ++s) {
      f32x4 sacc[4];
#pragma unroll
      for (int nt = 0; nt < 4; ++nt) sacc[nt] = zero;
#pragma unroll
      for (int nt = 0; nt < 4; ++nt) {
        sacc[nt] = __builtin_amdgcn_mfma_f32_16x16x32_bf16(qA0[s], kf0[nt], sacc[nt], 0, 0, 0);
        sacc[nt] = __builtin_amdgcn_mfma_f32_16x16x32_bf16(qA1[s], kf1[nt], sacc[nt], 0, 0, 0);
      }
      // mask + exp (C layout: row = l4*4+r, col = nt*16+l15)
#pragma unroll
      for (int r = 0; r < 4; ++r) {
        int gq = gqr[s][r];
        float acc = 0.f;
#pragma unroll
        for (int nt = 0; nt < 4; ++nt) {
          float sv = sacc[nt][r] + ((gq == gkv[nt]) ? -60.f : 0.f);
          float p = __expf(sv);
          acc += p;
          Ps[(w * 32 + s * 16 + l4 * 4 + r) * 72 + nt * 16 + l15] = (bf16_t)p;
        }
        rsum[s][r] += acc;
      }
    }
    __syncthreads();  // Ps write -> read ordering (wave-local regions, kept for safety)
#pragma unroll
    for (int s = 0; s < 2; ++s) {
      const bf16_t* pp = Ps + (w * 32 + s * 16 + l15) * 72;
      bf16x8 pf0 = *(const bf16x8*)(pp + l4 * 8);
      bf16x8 pf1 = *(const bf16x8*)(pp + 32 + l4 * 8);
#pragma unroll
      for (int nt = 0; nt < 4; ++nt) {
        bf16x8 vf0 = *(const bf16x8*)(Vs + (nt * 16 + l15) * 72 + l4 * 8);
        bf16x8 vf1 = *(const bf16x8*)(Vs + (nt * 16 + l15) * 72 + 32 + l4 * 8);
        oacc[s][nt] = __builtin_amdgcn_mfma_f32_16x16x32_bf16(pf0, vf0, oacc[s][nt], 0, 0, 0);
        oacc[s][nt] = __builtin_amdgcn_mfma_f32_16x16x32_bf16(pf1, vf1, oacc[s][nt], 0, 0, 0);
      }
    }
  }

  // one-time row-sum reduction across the 16 lanes of each row group
#pragma unroll
  for (int s = 0; s < 2; ++s)
#pragma unroll
    for (int r = 0; r < 4; ++r) {
      float t = rsum[s][r];
      t += __shfl_xor(t, 1, 64);
      t += __shfl_xor(t, 2, 64);
      t += __shfl_xor(t, 4, 64);
      t += __shfl_xor(t, 8, 64);
      rsum[s][r] = 1.f / t;
    }
#pragma unroll
  for (int s = 0; s < 2; ++s)
#pragma unroll
    for (int r = 0; r < 4; ++r) {
      int srow = qBase + w * 32 + s * 16 + l4 * 4 + r;
      float inv = rsum[s][r];
#pragma unroll
      for (int nt = 0; nt < 4; ++nt)
        outp[((size_t)(b * 1024 + srow)) * 1024 + h * 64 + nt * 16 + l15] =
            (bf16_t)(oacc[s][nt][r] * inv);
    }
}

// ---------------------------------------------------------------------------
// m97-style GEMM with split-K (blockIdx.z) and XOR-swizzled LDS.
// EPI: 1 = bias+gelu->bf16,  4 = f32 partial to Cf + z*M*N
// ---------------------------------------------------------------------------
__device__ __forceinline__ void stage16(const bf16_t* gp, bf16_t* lp) {
  __builtin_amdgcn_global_load_lds(
      (__attribute__((address_space(1))) void*)gp,
      (__attribute__((address_space(3))) void*)lp, 16, 0, 0);
}

template <int EPI>
__global__ __launch_bounds__(256, 2) void gemm_bt(
    const bf16_t* __restrict__ A, const bf16_t* __restrict__ Bt,
    int M, int N, int Kd, int kChunk,
    float* __restrict__ Cf, bf16_t* __restrict__ Cb,
    const float* __restrict__ bias)
{
  __shared__ bf16_t sA[128 * 32];
  __shared__ bf16_t sB[128 * 32];
  const int tid = threadIdx.x;
  const int lane = tid & 63, w = tid >> 6;
  const int wr = w >> 1, wc = w & 1;
  const int rowBase = blockIdx.y * 128;
  const int colBase = blockIdx.x * 128;
  const int l15 = lane & 15, l4 = lane >> 4;
  const int sr = lane >> 2;
  const int scc = (((lane & 3) ^ ((sr >> 1) & 3))) * 8;  // XOR-swizzled granule
  const int l4s = l4 ^ ((l15 >> 1) & 3);                 // matching read swizzle

  const f32x4 zero = {0.f, 0.f, 0.f, 0.f};
  f32x4 acc[4][4];
#pragma unroll
  for (int i = 0; i < 4; ++i)
#pragma unroll
    for (int j = 0; j < 4; ++j) acc[i][j] = zero;

  const bf16_t* aBase = A + (size_t)(rowBase + w * 32 + sr) * Kd + scc;
  const bf16_t* bBase = Bt + (size_t)(colBase + w * 32 + sr) * Kd + scc;

  const int kStart = blockIdx.z * kChunk;
  for (int k0 = kStart; k0 < kStart + kChunk; k0 += 32) {
    __syncthreads();
#pragma unroll
    for (int i = 0; i < 2; ++i) {
      stage16(aBase + (size_t)i * 16 * Kd + k0, sA + (w * 32 + i * 16) * 32);
      stage16(bBase + (size_t)i * 16 * Kd + k0, sB + (w * 32 + i * 16) * 32);
    }
    __syncthreads();
    bf16x8 af[4], bfr[4];
#pragma unroll
    for (int mt = 0; mt < 4; ++mt)
      af[mt] = *(const bf16x8*)(sA + (wr * 64 + mt * 16 + l15) * 32 + l4s * 8);
#pragma unroll
    for (int nt = 0; nt < 4; ++nt)
      bfr[nt] = *(const bf16x8*)(sB + (wc * 64 + nt * 16 + l15) * 32 + l4s * 8);
#pragma unroll
    for (int mt = 0; mt < 4; ++mt)
#pragma unroll
      for (int nt = 0; nt < 4; ++nt)
        acc[mt][nt] = __builtin_amdgcn_mfma_f32_16x16x32_bf16(af[mt], bfr[nt],
                                                              acc[mt][nt], 0, 0, 0);
  }

  const size_t zOff = (size_t)blockIdx.z * M * N;
#pragma unroll
  for (int mt = 0; mt < 4; ++mt) {
#pragma unroll
    for (int nt = 0; nt < 4; ++nt) {
      int col = colBase + wc * 64 + nt * 16 + l15;
#pragma unroll
      for (int r = 0; r < 4; ++r) {
        int rr = rowBase + wr * 64 + mt * 16 + l4 * 4 + r;
        float v = acc[mt][nt][r];
        if constexpr (EPI == 1) {
          float t = v + bias[col];
          float g = 0.5f * t *
                    (1.0f + tanhf(0.7978845608028654f * (t + 0.044715f * t * t * t)));
          Cb[(size_t)rr * N + col] = (bf16_t)g;
        } else {
          Cf[zOff + (size_t)rr * N + col] = v;
        }
      }
    }
  }
}

// ---------------------------------------------------------------------------
// Fused: Wo split-K reduce + msa gate + residual + query gate -> xbuf (f32),
// then LN2 + mlp modulation -> xn_mod (bf16).  One block per row.
// ---------------------------------------------------------------------------
__global__ __launch_bounds__(256) void ln2_fused_kernel(
    const float* __restrict__ P0, const float* __restrict__ P1,
    const float* __restrict__ qx, const float* __restrict__ n2w,
    const float* __restrict__ mod, const int* __restrict__ qen,
    float* __restrict__ xbuf, bf16_t* __restrict__ xnmod)
{
  int row = blockIdx.x;
  int b = row >> 10;
  int tid = threadIdx.x;
  bool en = qen[row] != 0;
  float4 p0 = ((const float4*)(P0 + (size_t)row * 1024))[tid];
  float4 p1 = ((const float4*)(P1 + (size_t)row * 1024))[tid];
  float4 res = ((const float4*)(qx + (size_t)row * 1024))[tid];
  float4 g = ((const float4*)(mod + b * 6144 + 2048))[tid];
  float4 x;
  x.x = en ? fmaf(g.x, p0.x + p1.x, res.x) : res.x;
  x.y = en ? fmaf(g.y, p0.y + p1.y, res.y) : res.y;
  x.z = en ? fmaf(g.z, p0.z + p1.z, res.z) : res.z;
  x.w = en ? fmaf(g.w, p0.w + p1.w, res.w) : res.w;
  ((float4*)(xbuf + (size_t)row * 1024))[tid] = x;

  float s = x.x + x.y + x.z + x.w;
  float s2 = x.x * x.x + x.y * x.y + x.z * x.z + x.w * x.w;
#pragma unroll
  for (int off = 32; off > 0; off >>= 1) {
    s += __shfl_down(s, off, 64);
    s2 += __shfl_down(s2, off, 64);
  }
  __shared__ float ps[4], ps2[4];
  if ((tid & 63) == 0) { ps[tid >> 6] = s; ps2[tid >> 6] = s2; }
  __syncthreads();
  float mu = (ps[0] + ps[1] + ps[2] + ps[3]) * (1.0f / 1024.0f);
  float var = (ps2[0] + ps2[1] + ps2[2] + ps2[3]) * (1.0f / 1024.0f) - mu * mu;
  float rs = rsqrtf(var + 1e-5f);
  float4 sc = ((const float4*)(mod + b * 6144 + 4096))[tid];
  float4 sh = ((const float4*)(mod + b * 6144 + 3072))[tid];
  float4 wv = ((const float4*)n2w)[tid];
  float xv[4] = {x.x, x.y, x.z, x.w};
  float scv[4] = {sc.x, sc.y, sc.z, sc.w};
  float shv[4] = {sh.x, sh.y, sh.z, sh.w};
  float wvv[4] = {wv.x, wv.y, wv.z, wv.w};
#pragma unroll
  for (int i = 0; i < 4; ++i) {
    float n = (xv[i] - mu) * rs * wvv[i];
    n = n * (1.0f + scv[i]) + shv[i];
    xnmod[(size_t)row * 1024 + tid * 4 + i] = (bf16_t)n;
  }
}

// ---------------------------------------------------------------------------
// Final: W2 split-4 reduce + bias + mlp gate + residual + query gate -> out f32
// ---------------------------------------------------------------------------
__global__ __launch_bounds__(256) void final_reduce_kernel(
    const float* __restrict__ P, const float* __restrict__ b2,
    const float* __restrict__ mod, const int* __restrict__ qen,
    const float* __restrict__ xbuf, float* __restrict__ out)
{
  int row = blockIdx.x;
  int b = row >> 10;
  int tid = threadIdx.x;
  bool en = qen[row] != 0;
  size_t ro = (size_t)row * 1024;
  float4 p0 = ((const float4*)(P + ro))[tid];
  float4 p1 = ((const float4*)(P + 4194304 + ro))[tid];
  float4 p2 = ((const float4*)(P + 2 * 4194304 + ro))[tid];
  float4 p3 = ((const float4*)(P + 3 * 4194304 + ro))[tid];
  float4 bb = ((const float4*)b2)[tid];
  float4 xm = ((const float4*)(xbuf + ro))[tid];
  float4 g = ((const float4*)(mod + b * 6144 + 5120))[tid];
  float4 o;
  o.x = en ? fmaf(g.x, p0.x + p1.x + p2.x + p3.x + bb.x, xm.x) : xm.x;
  o.y = en ? fmaf(g.y, p0.y + p1.y + p2.y + p3.y + bb.y, xm.y) : xm.y;
  o.z = en ? fmaf(g.z, p0.z + p1.z + p2.z + p3.z + bb.z, xm.z) : xm.z;
  o.w = en ? fmaf(g.w, p0.w + p1.w + p2.w + p3.w + bb.w, xm.w) : xm.w;
  ((float4*)(out + ro))[tid] = o;
}

// ---------------------------------------------------------------------------
extern "C" void kernel_launch(void* const* d_in, const int* in_sizes, int n_in,
                              void* d_out, int out_size, void* d_ws, size_t ws_size,
                              hipStream_t stream)
{
  const float* q_x    = (const float*)d_in[0];
  const float* kv_x   = (const float*)d_in[1];
  const float* t_cond = (const float*)d_in[2];
  const float* cos_q  = (const float*)d_in[3];
  const float* sin_q  = (const float*)d_in[4];
  const float* cos_k  = (const float*)d_in[5];
  const float* sin_k  = (const float*)d_in[6];
  const int*   grp    = (const int*)d_in[7];
  const int*   qen    = (const int*)d_in[8];
  const float* qn_w   = (const float*)d_in[9];
  const float* kvn_w  = (const float*)d_in[10];
  const float* n2_w   = (const float*)d_in[11];
  const float* Wq     = (const float*)d_in[12];
  const float* Wkv    = (const float*)d_in[13];
  const float* Wo     = (const float*)d_in[14];
  const float* W1     = (const float*)d_in[15];
  const float* b1     = (const float*)d_in[16];
  const float* W2     = (const float*)d_in[17];
  const float* b2     = (const float*)d_in[18];
  const float* adaW   = (const float*)d_in[19];
  const float* adab   = (const float*)d_in[20];
  float* out = (float*)d_out;

  char* ws = (char*)d_ws;
  const size_t MB = 1ull << 20;
  float*  mod    = (float*)(ws + 0);                  // 96 KB, whole call
  bf16_t* Wq_t   = (bf16_t*)(ws + 98304);             // 2 MB
  bf16_t* Wkv_t  = (bf16_t*)(ws + 98304 + 2 * MB);    // 4 MB
  bf16_t* Wo_t   = (bf16_t*)(ws + 98304 + 6 * MB);    // 2 MB
  bf16_t* W1_t   = (bf16_t*)(ws + 98304 + 8 * MB);    // 8 MB
  bf16_t* W2_t   = (bf16_t*)(ws + 98304 + 16 * MB);   // 8 MB
  bf16_t* qn_mod = (bf16_t*)(ws + 98304 + 24 * MB);   // 8 MB; reused as xn_mod
  bf16_t* kvn    = (bf16_t*)(ws + 98304 + 32 * MB);   // 8 MB; reused as attn_o
  bf16_t* q_r    = (bf16_t*)(ws + 98304 + 40 * MB);   // 8 MB; [q_r,k_r] reused as xbuf
  bf16_t* k_r    = (bf16_t*)(ws + 98304 + 48 * MB);   // 8 MB
  bf16_t* v_t    = (bf16_t*)(ws + 98304 + 56 * MB);   // 8 MB
  bf16_t* h1     = (bf16_t*)(ws + 98304 + 64 * MB);   // 32 MB
  float*  scr    = (float*)(ws + 98304 + 96 * MB);    // 64 MB split-K partials
  bf16_t* xn_mod = qn_mod;
  bf16_t* attn_o = kvn;
  float*  xbuf   = (float*)q_r;

  // 1. adaLN modulation (split-K + atomics)
  mod_init_kernel<<<96, 256, 0, stream>>>(adab, mod);
  mod_partial_kernel<<<dim3(24, 8), 256, 0, stream>>>(t_cond, adaW, mod);
  // 2. weight prep (transpose + bf16)
  transpose_to_bf16<<<dim3(32, 32),  dim3(32, 8), 0, stream>>>(Wq,  Wq_t,  1024, 1024);
  transpose_to_bf16<<<dim3(64, 32),  dim3(32, 8), 0, stream>>>(Wkv, Wkv_t, 1024, 2048);
  transpose_to_bf16<<<dim3(32, 32),  dim3(32, 8), 0, stream>>>(Wo,  Wo_t,  1024, 1024);
  transpose_to_bf16<<<dim3(128, 32), dim3(32, 8), 0, stream>>>(W1,  W1_t,  1024, 4096);
  transpose_to_bf16<<<dim3(32, 128), dim3(32, 8), 0, stream>>>(W2,  W2_t,  4096, 1024);
  // 3. LayerNorms
  ln_mod_kernel<<<4096, 256, 0, stream>>>(q_x,  qn_w,  mod, 1, 0, 1024, qn_mod);
  ln_mod_kernel<<<4096, 256, 0, stream>>>(kv_x, kvn_w, mod, 0, 0, 0,    kvn);
  // 4. Q proj (split-2) + reduce/RoPE
  gemm_bt<4><<<dim3(8, 32, 2), 256, 0, stream>>>(qn_mod, Wq_t, 4096, 1024, 1024, 512,
                                                 scr, nullptr, nullptr);
  reduce_q_rope_kernel<<<8192, 256, 0, stream>>>(scr, scr + 4194304, cos_q, sin_q, q_r);
  // 5. KV proj (split-2) + reduce/RoPE/V-transpose
  gemm_bt<4><<<dim3(16, 32, 2), 256, 0, stream>>>(kvn, Wkv_t, 4096, 2048, 1024, 512,
                                                  scr, nullptr, nullptr);
  reduce_kv_kernel<<<dim3(64, 16), 256, 0, stream>>>(scr, scr + 8388608, cos_k, sin_k,
                                                     k_r, v_t);
  // 6. attention (128-row Q tiles)
  attn_kernel<<<dim3(64, 8), 256, 0, stream>>>(q_r, k_r, v_t, grp, attn_o);
  // 7. output proj (split-2) + fused reduce/gate/residual/LN2
  gemm_bt<4><<<dim3(8, 32, 2), 256, 0, stream>>>(attn_o, Wo_t, 4096, 1024, 1024, 512,
                                                 scr, nullptr, nullptr);
  ln2_fused_kernel<<<4096, 256, 0, stream>>>(scr, scr + 4194304, q_x, n2_w, mod, qen,
                                             xbuf, xn_mod);
  // 8. MLP up + gelu
  gemm_bt<1><<<dim3(32, 32, 1), 256, 0, stream>>>(xn_mod, W1_t, 4096, 4096, 1024, 1024,
                                                  nullptr, h1, b1);
  // 9. MLP down (split-4) + final fused reduce -> out
  gemm_bt<4><<<dim3(8, 32, 4), 256, 0, stream>>>(h1, W2_t, 4096, 1024, 4096, 1024,
                                                 scr, nullptr, nullptr);
  final_reduce_kernel<<<4096, 256, 0, stream>>>(scr, b2, mod, qen, xbuf, out);
}

// Round 4
// 451.226 us; speedup vs baseline: 1.3725x; 1.0727x over previous
//
#include <hip/hip_runtime.h>
#include <hip/hip_bf16.h>
#include <math.h>

typedef __bf16 bf16_t;
typedef __attribute__((ext_vector_type(8))) __bf16 bf16x8;
typedef __attribute__((ext_vector_type(4))) __bf16 bf16x4;
typedef __attribute__((ext_vector_type(4))) float f32x4;

// ---------------------------------------------------------------------------
// mod init: mod[b][c] = adab[c]
// ---------------------------------------------------------------------------
__global__ __launch_bounds__(256) void mod_init_kernel(
    const float* __restrict__ adab, float* __restrict__ mod)
{
  int i = blockIdx.x * 256 + threadIdx.x;  // < 24576
  int b = i / 6144, c = i - b * 6144;
  mod[i] = adab[c];
  (void)b;
}

// ---------------------------------------------------------------------------
// mod partial: split-K over the 1024 reduction dim, atomicAdd into mod.
// grid (24, 8) x 256
// ---------------------------------------------------------------------------
__global__ __launch_bounds__(256) void mod_partial_kernel(
    const float* __restrict__ tc, const float* __restrict__ adaW,
    float* __restrict__ mod)
{
  __shared__ float st[4][128];
  int tid = threadIdx.x, z = blockIdx.y;
  for (int i = tid; i < 512; i += 256)
    st[i >> 7][i & 127] = tc[(i >> 7) * 1024 + z * 128 + (i & 127)];
  __syncthreads();
  int col = blockIdx.x * 256 + tid;
  float a0 = 0.f, a1 = 0.f, a2 = 0.f, a3 = 0.f;
  for (int k = 0; k < 128; ++k) {
    float wv = adaW[(size_t)(z * 128 + k) * 6144 + col];
    a0 = fmaf(st[0][k], wv, a0);
    a1 = fmaf(st[1][k], wv, a1);
    a2 = fmaf(st[2][k], wv, a2);
    a3 = fmaf(st[3][k], wv, a3);
  }
  atomicAdd(&mod[col], a0);
  atomicAdd(&mod[6144 + col], a1);
  atomicAdd(&mod[2 * 6144 + col], a2);
  atomicAdd(&mod[3 * 6144 + col], a3);
}

// ---------------------------------------------------------------------------
// Transposing f32 -> bf16 weight prep: out[c][r] = (bf16) in[r][c]
// ---------------------------------------------------------------------------
__global__ __launch_bounds__(256) void transpose_to_bf16(
    const float* __restrict__ in, bf16_t* __restrict__ out, int R, int C)
{
  __shared__ float tile[32][33];
  int c0 = blockIdx.x * 32, r0 = blockIdx.y * 32;
  int tx = threadIdx.x, ty = threadIdx.y;
#pragma unroll
  for (int i = 0; i < 4; ++i)
    tile[ty + i * 8][tx] = in[(size_t)(r0 + ty + i * 8) * C + c0 + tx];
  __syncthreads();
#pragma unroll
  for (int i = 0; i < 4; ++i)
    out[(size_t)(c0 + ty + i * 8) * R + r0 + tx] = (bf16_t)tile[tx][ty + i * 8];
}

// ---------------------------------------------------------------------------
// LayerNorm (+ optional adaLN shift/scale) -> bf16.  One block per row (D=1024).
// ---------------------------------------------------------------------------
__global__ __launch_bounds__(256) void ln_mod_kernel(
    const float* __restrict__ x, const float* __restrict__ wgt,
    const float* __restrict__ mod, int useMod, int shOff, int scOff,
    bf16_t* __restrict__ out)
{
  int row = blockIdx.x;
  int b = row >> 10;
  int tid = threadIdx.x;
  const float* xr = x + (size_t)row * 1024;
  float4 v = ((const float4*)xr)[tid];
  float s = v.x + v.y + v.z + v.w;
  float s2 = v.x * v.x + v.y * v.y + v.z * v.z + v.w * v.w;
#pragma unroll
  for (int off = 32; off > 0; off >>= 1) {
    s += __shfl_down(s, off, 64);
    s2 += __shfl_down(s2, off, 64);
  }
  __shared__ float ps[4], ps2[4];
  if ((tid & 63) == 0) { ps[tid >> 6] = s; ps2[tid >> 6] = s2; }
  __syncthreads();
  float mu = (ps[0] + ps[1] + ps[2] + ps[3]) * (1.0f / 1024.0f);
  float var = (ps2[0] + ps2[1] + ps2[2] + ps2[3]) * (1.0f / 1024.0f) - mu * mu;
  float rs = rsqrtf(var + 1e-5f);
  float xv[4] = {v.x, v.y, v.z, v.w};
#pragma unroll
  for (int i = 0; i < 4; ++i) {
    int col = tid * 4 + i;
    float n = (xv[i] - mu) * rs * wgt[col];
    if (useMod)
      n = n * (1.0f + mod[b * 6144 + scOff + col]) + mod[b * 6144 + shOff + col];
    out[(size_t)row * 1024 + col] = (bf16_t)n;
  }
}

// ---------------------------------------------------------------------------
// Reduce split-K bf16 partials of Q proj + RoPE + scale -> q_r (B,H,S,64) bf16
// ---------------------------------------------------------------------------
__global__ __launch_bounds__(256) void reduce_q_rope_kernel(
    const bf16_t* __restrict__ P0, const bf16_t* __restrict__ P1,
    const float* __restrict__ cosq, const float* __restrict__ sinq,
    bf16_t* __restrict__ qr)
{
  int t = blockIdx.x * 256 + threadIdx.x;  // < 2M
  int hd = t & 31;
  int h = (t >> 5) & 15;
  int s = (t >> 9) & 1023;
  int b = t >> 19;
  size_t base = ((size_t)(b * 1024 + s)) * 1024 + h * 64 + hd;
  float v1 = (float)P0[base] + (float)P1[base];
  float v2 = (float)P0[base + 32] + (float)P1[base + 32];
  float c1 = cosq[s * 64 + hd], s1 = sinq[s * 64 + hd];
  float c2 = cosq[s * 64 + hd + 32], s2 = sinq[s * 64 + hd + 32];
  float o1 = (v1 * c1 - v2 * s1) * 0.125f;
  float o2 = (v2 * c2 + v1 * s2) * 0.125f;
  size_t ob = ((size_t)(b * 16 + h) * 1024 + s) * 64 + hd;
  qr[ob] = (bf16_t)o1;
  qr[ob + 32] = (bf16_t)o2;
}

// ---------------------------------------------------------------------------
// Reduce split-K bf16 partials of KV proj: RoPE on K -> k_r (B,H,K,64);
// V transposed via LDS -> v_t (B,H,64,K).  grid (64 bh, 16 ntile) x 256
// ---------------------------------------------------------------------------
__global__ __launch_bounds__(256) void reduce_kv_kernel(
    const bf16_t* __restrict__ P0, const bf16_t* __restrict__ P1,
    const float* __restrict__ cosk, const float* __restrict__ sink,
    bf16_t* __restrict__ kr, bf16_t* __restrict__ vt)
{
  __shared__ float ks[64][65];
  __shared__ float vs[64][65];
  int bh = blockIdx.x;
  int b = bh >> 4, h = bh & 15;
  int n0 = blockIdx.y * 64;
  int tid = threadIdx.x;
#pragma unroll
  for (int it = 0; it < 16; ++it) {
    int linear = tid + it * 256;
    int nl = linear >> 6, hd = linear & 63;
    size_t gi = ((size_t)(b * 1024 + n0 + nl)) * 2048 + h * 64 + hd;
    ks[nl][hd] = (float)P0[gi] + (float)P1[gi];
    vs[hd][nl] = (float)P0[gi + 1024] + (float)P1[gi + 1024];
  }
  __syncthreads();
#pragma unroll
  for (int it = 0; it < 16; ++it) {
    int linear = tid + it * 256;
    int nl = linear >> 6, hd = linear & 63;
    float kv = ks[nl][hd];
    float pv = ks[nl][hd ^ 32];
    float c = cosk[(n0 + nl) * 64 + hd], sn = sink[(n0 + nl) * 64 + hd];
    float o = (hd < 32) ? (kv * c - pv * sn) : (kv * c + pv * sn);
    kr[((size_t)bh * 1024 + n0 + nl) * 64 + hd] = (bf16_t)o;
    int rh = linear >> 6, nn = linear & 63;  // reuse for v store
    vt[((size_t)bh * 64 + rh) * 1024 + n0 + nn] = (bf16_t)vs[rh][nn];
  }
}

// ---------------------------------------------------------------------------
// Flash-style attention, NO online softmax (scores are O(1); softmax is
// shift-invariant, so accumulate exp(s) directly, normalize once at the end).
// 128-row Q tile per block; wave w owns rows [32w,32w+32) as 2 strips of 16.
// ---------------------------------------------------------------------------
__global__ __launch_bounds__(256, 2) void attn_kernel(
    const bf16_t* __restrict__ qr, const bf16_t* __restrict__ kr,
    const bf16_t* __restrict__ vt, const int* __restrict__ grp,
    bf16_t* __restrict__ outp)
{
  __shared__ bf16_t Ks[64 * 72];
  __shared__ bf16_t Vs[64 * 72];
  __shared__ bf16_t Ps[128 * 72];
  __shared__ int gk[64];
  const int bh = blockIdx.x;
  const int b = bh >> 4, h = bh & 15;
  const int qBase = blockIdx.y * 128;
  const int tid = threadIdx.x, lane = tid & 63, w = tid >> 6;
  const int l15 = lane & 15, l4 = lane >> 4;
  const f32x4 zero = {0.f, 0.f, 0.f, 0.f};

  bf16x8 qA0[2], qA1[2];
  int gqr[2][4];
#pragma unroll
  for (int s = 0; s < 2; ++s) {
    int row = qBase + w * 32 + s * 16;
    const bf16_t* qp = qr + ((size_t)bh * 1024 + row + l15) * 64;
    qA0[s] = *(const bf16x8*)(qp + l4 * 8);
    qA1[s] = *(const bf16x8*)(qp + 32 + l4 * 8);
#pragma unroll
    for (int r = 0; r < 4; ++r) gqr[s][r] = grp[b * 1024 + row + l4 * 4 + r];
  }

  f32x4 oacc[2][4];
  float rsum[2][4];
#pragma unroll
  for (int s = 0; s < 2; ++s)
#pragma unroll
    for (int i = 0; i < 4; ++i) { oacc[s][i] = zero; rsum[s][i] = 0.f; }

  for (int kt = 0; kt < 16; ++kt) {
    __syncthreads();
#pragma unroll
    for (int i = 0; i < 2; ++i) {
      int c = tid * 2 + i;
      int r = c >> 3, cc = (c & 7) * 8;
      *(bf16x8*)(Ks + r * 72 + cc) =
          *(const bf16x8*)(kr + ((size_t)bh * 1024 + kt * 64 + r) * 64 + cc);
      *(bf16x8*)(Vs + r * 72 + cc) =
          *(const bf16x8*)(vt + ((size_t)bh * 64 + r) * 1024 + kt * 64 + cc);
    }
    if (tid < 64) gk[tid] = grp[b * 1024 + kt * 64 + tid];
    __syncthreads();

    int gkv[4];
    bf16x8 kf0[4], kf1[4];
#pragma unroll
    for (int nt = 0; nt < 4; ++nt) {
      gkv[nt] = gk[nt * 16 + l15];
      kf0[nt] = *(const bf16x8*)(Ks + (nt * 16 + l15) * 72 + l4 * 8);
      kf1[nt] = *(const bf16x8*)(Ks + (nt * 16 + l15) * 72 + 32 + l4 * 8);
    }

#pragma unroll
    for (int s = 0; s < 2; ++s) {
      f32x4 sacc[4];
#pragma unroll
      for (int nt = 0; nt < 4; ++nt) sacc[nt] = zero;
#pragma unroll
      for (int nt = 0; nt < 4; ++nt) {
        sacc[nt] = __builtin_amdgcn_mfma_f32_16x16x32_bf16(qA0[s], kf0[nt], sacc[nt], 0, 0, 0);
        sacc[nt] = __builtin_amdgcn_mfma_f32_16x16x32_bf16(qA1[s], kf1[nt], sacc[nt], 0, 0, 0);
      }
#pragma unroll
      for (int r = 0; r < 4; ++r) {
        int gq = gqr[s][r];
        float acc = 0.f;
#pragma unroll
        for (int nt = 0; nt < 4; ++nt) {
          float sv = sacc[nt][r] + ((gq == gkv[nt]) ? -60.f : 0.f);
          float p = __expf(sv);
          acc += p;
          Ps[(w * 32 + s * 16 + l4 * 4 + r) * 72 + nt * 16 + l15] = (bf16_t)p;
        }
        rsum[s][r] += acc;
      }
    }
    __syncthreads();
#pragma unroll
    for (int s = 0; s < 2; ++s) {
      const bf16_t* pp = Ps + (w * 32 + s * 16 + l15) * 72;
      bf16x8 pf0 = *(const bf16x8*)(pp + l4 * 8);
      bf16x8 pf1 = *(const bf16x8*)(pp + 32 + l4 * 8);
#pragma unroll
      for (int nt = 0; nt < 4; ++nt) {
        bf16x8 vf0 = *(const bf16x8*)(Vs + (nt * 16 + l15) * 72 + l4 * 8);
        bf16x8 vf1 = *(const bf16x8*)(Vs + (nt * 16 + l15) * 72 + 32 + l4 * 8);
        oacc[s][nt] = __builtin_amdgcn_mfma_f32_16x16x32_bf16(pf0, vf0, oacc[s][nt], 0, 0, 0);
        oacc[s][nt] = __builtin_amdgcn_mfma_f32_16x16x32_bf16(pf1, vf1, oacc[s][nt], 0, 0, 0);
      }
    }
  }

#pragma unroll
  for (int s = 0; s < 2; ++s)
#pragma unroll
    for (int r = 0; r < 4; ++r) {
      float t = rsum[s][r];
      t += __shfl_xor(t, 1, 64);
      t += __shfl_xor(t, 2, 64);
      t += __shfl_xor(t, 4, 64);
      t += __shfl_xor(t, 8, 64);
      rsum[s][r] = 1.f / t;
    }
#pragma unroll
  for (int s = 0; s < 2; ++s)
#pragma unroll
    for (int r = 0; r < 4; ++r) {
      int srow = qBase + w * 32 + s * 16 + l4 * 4 + r;
      float inv = rsum[s][r];
#pragma unroll
      for (int nt = 0; nt < 4; ++nt)
        outp[((size_t)(b * 1024 + srow)) * 1024 + h * 64 + nt * 16 + l15] =
            (bf16_t)(oacc[s][nt][r] * inv);
    }
}

// ---------------------------------------------------------------------------
// m97-style GEMM: split-K (blockIdx.z), XOR-swizzled LDS, XCD-aware tile map.
// EPI: 1 = bias+gelu->bf16,  4 = bf16 partial to Cb + z*M*N
// XCD map: linear block id L (x fastest, z excluded); xcd = L&7; each XCD owns
// a (gy/4 x gx/2) patch of tiles -> per-XCD L2 working set <= ~3 MB.
// ---------------------------------------------------------------------------
__device__ __forceinline__ void stage16(const bf16_t* gp, bf16_t* lp) {
  __builtin_amdgcn_global_load_lds(
      (__attribute__((address_space(1))) void*)gp,
      (__attribute__((address_space(3))) void*)lp, 16, 0, 0);
}

template <int EPI>
__global__ __launch_bounds__(256, 2) void gemm_bt(
    const bf16_t* __restrict__ A, const bf16_t* __restrict__ Bt,
    int M, int N, int Kd, int kChunk,
    bf16_t* __restrict__ Cb,
    const float* __restrict__ bias)
{
  __shared__ bf16_t sA[128 * 32];
  __shared__ bf16_t sB[128 * 32];
  const int tid = threadIdx.x;
  const int lane = tid & 63, w = tid >> 6;
  const int wr = w >> 1, wc = w & 1;

  // XCD-aware tile remap (requires gy%4==0, gx%2==0, gx*gy%8==0)
  const int gx = gridDim.x, gy = gridDim.y;
  const int L = blockIdx.y * gx + blockIdx.x;
  const int xcd = L & 7, idx = L >> 3;
  const int ry = gy >> 2, rx = gx >> 1;
  const int tileY = (xcd & 3) * ry + (idx % ry);
  const int tileX = (xcd >> 2) * rx + (idx / ry);
  const int rowBase = tileY * 128;
  const int colBase = tileX * 128;

  const int l15 = lane & 15, l4 = lane >> 4;
  const int sr = lane >> 2;
  const int scc = (((lane & 3) ^ ((sr >> 1) & 3))) * 8;  // XOR-swizzled granule
  const int l4s = l4 ^ ((l15 >> 1) & 3);                 // matching read swizzle

  const f32x4 zero = {0.f, 0.f, 0.f, 0.f};
  f32x4 acc[4][4];
#pragma unroll
  for (int i = 0; i < 4; ++i)
#pragma unroll
    for (int j = 0; j < 4; ++j) acc[i][j] = zero;

  const bf16_t* aBase = A + (size_t)(rowBase + w * 32 + sr) * Kd + scc;
  const bf16_t* bBase = Bt + (size_t)(colBase + w * 32 + sr) * Kd + scc;

  const int kStart = blockIdx.z * kChunk;
  for (int k0 = kStart; k0 < kStart + kChunk; k0 += 32) {
    __syncthreads();
#pragma unroll
    for (int i = 0; i < 2; ++i) {
      stage16(aBase + (size_t)i * 16 * Kd + k0, sA + (w * 32 + i * 16) * 32);
      stage16(bBase + (size_t)i * 16 * Kd + k0, sB + (w * 32 + i * 16) * 32);
    }
    __syncthreads();
    bf16x8 af[4], bfr[4];
#pragma unroll
    for (int mt = 0; mt < 4; ++mt)
      af[mt] = *(const bf16x8*)(sA + (wr * 64 + mt * 16 + l15) * 32 + l4s * 8);
#pragma unroll
    for (int nt = 0; nt < 4; ++nt)
      bfr[nt] = *(const bf16x8*)(sB + (wc * 64 + nt * 16 + l15) * 32 + l4s * 8);
#pragma unroll
    for (int mt = 0; mt < 4; ++mt)
#pragma unroll
      for (int nt = 0; nt < 4; ++nt)
        acc[mt][nt] = __builtin_amdgcn_mfma_f32_16x16x32_bf16(af[mt], bfr[nt],
                                                              acc[mt][nt], 0, 0, 0);
  }

  const size_t zOff = (size_t)blockIdx.z * M * N;
#pragma unroll
  for (int mt = 0; mt < 4; ++mt) {
#pragma unroll
    for (int nt = 0; nt < 4; ++nt) {
      int col = colBase + wc * 64 + nt * 16 + l15;
#pragma unroll
      for (int r = 0; r < 4; ++r) {
        int rr = rowBase + wr * 64 + mt * 16 + l4 * 4 + r;
        float v = acc[mt][nt][r];
        if constexpr (EPI == 1) {
          float t = v + bias[col];
          float z = 0.7978845608028654f * (t + 0.044715f * t * t * t);
          float e = __expf(2.f * z);
          float g = 0.5f * t * (2.f - 2.f / (e + 1.f));
          Cb[(size_t)rr * N + col] = (bf16_t)g;
        } else {
          Cb[zOff + (size_t)rr * N + col] = (bf16_t)v;
        }
      }
    }
  }
}

// ---------------------------------------------------------------------------
// Fused: Wo split-K reduce + msa gate + residual + query gate -> xbuf (f32),
// then LN2 + mlp modulation -> xn_mod (bf16).  One block per row.
// ---------------------------------------------------------------------------
__global__ __launch_bounds__(256) void ln2_fused_kernel(
    const bf16_t* __restrict__ P0, const bf16_t* __restrict__ P1,
    const float* __restrict__ qx, const float* __restrict__ n2w,
    const float* __restrict__ mod, const int* __restrict__ qen,
    float* __restrict__ xbuf, bf16_t* __restrict__ xnmod)
{
  int row = blockIdx.x;
  int b = row >> 10;
  int tid = threadIdx.x;
  bool en = qen[row] != 0;
  bf16x4 p0 = *(const bf16x4*)(P0 + (size_t)row * 1024 + tid * 4);
  bf16x4 p1 = *(const bf16x4*)(P1 + (size_t)row * 1024 + tid * 4);
  float4 res = ((const float4*)(qx + (size_t)row * 1024))[tid];
  float4 g = ((const float4*)(mod + b * 6144 + 2048))[tid];
  float4 x;
  x.x = en ? fmaf(g.x, (float)p0[0] + (float)p1[0], res.x) : res.x;
  x.y = en ? fmaf(g.y, (float)p0[1] + (float)p1[1], res.y) : res.y;
  x.z = en ? fmaf(g.z, (float)p0[2] + (float)p1[2], res.z) : res.z;
  x.w = en ? fmaf(g.w, (float)p0[3] + (float)p1[3], res.w) : res.w;
  ((float4*)(xbuf + (size_t)row * 1024))[tid] = x;

  float s = x.x + x.y + x.z + x.w;
  float s2 = x.x * x.x + x.y * x.y + x.z * x.z + x.w * x.w;
#pragma unroll
  for (int off = 32; off > 0; off >>= 1) {
    s += __shfl_down(s, off, 64);
    s2 += __shfl_down(s2, off, 64);
  }
  __shared__ float ps[4], ps2[4];
  if ((tid & 63) == 0) { ps[tid >> 6] = s; ps2[tid >> 6] = s2; }
  __syncthreads();
  float mu = (ps[0] + ps[1] + ps[2] + ps[3]) * (1.0f / 1024.0f);
  float var = (ps2[0] + ps2[1] + ps2[2] + ps2[3]) * (1.0f / 1024.0f) - mu * mu;
  float rs = rsqrtf(var + 1e-5f);
  float4 sc = ((const float4*)(mod + b * 6144 + 4096))[tid];
  float4 sh = ((const float4*)(mod + b * 6144 + 3072))[tid];
  float4 wv = ((const float4*)n2w)[tid];
  float xv[4] = {x.x, x.y, x.z, x.w};
  float scv[4] = {sc.x, sc.y, sc.z, sc.w};
  float shv[4] = {sh.x, sh.y, sh.z, sh.w};
  float wvv[4] = {wv.x, wv.y, wv.z, wv.w};
#pragma unroll
  for (int i = 0; i < 4; ++i) {
    float n = (xv[i] - mu) * rs * wvv[i];
    n = n * (1.0f + scv[i]) + shv[i];
    xnmod[(size_t)row * 1024 + tid * 4 + i] = (bf16_t)n;
  }
}

// ---------------------------------------------------------------------------
// Final: W2 split-4 reduce + bias + mlp gate + residual + query gate -> out f32
// ---------------------------------------------------------------------------
__global__ __launch_bounds__(256) void final_reduce_kernel(
    const bf16_t* __restrict__ P, const float* __restrict__ b2,
    const float* __restrict__ mod, const int* __restrict__ qen,
    const float* __restrict__ xbuf, float* __restrict__ out)
{
  int row = blockIdx.x;
  int b = row >> 10;
  int tid = threadIdx.x;
  bool en = qen[row] != 0;
  size_t ro = (size_t)row * 1024 + tid * 4;
  bf16x4 p0 = *(const bf16x4*)(P + ro);
  bf16x4 p1 = *(const bf16x4*)(P + 4194304 + ro);
  bf16x4 p2 = *(const bf16x4*)(P + 2 * 4194304 + ro);
  bf16x4 p3 = *(const bf16x4*)(P + 3 * 4194304 + ro);
  float4 bb = ((const float4*)b2)[tid];
  float4 xm = *(const float4*)(xbuf + ro);
  float4 g = ((const float4*)(mod + b * 6144 + 5120))[tid];
  float4 o;
  float v0 = (float)p0[0] + (float)p1[0] + (float)p2[0] + (float)p3[0] + bb.x;
  float v1 = (float)p0[1] + (float)p1[1] + (float)p2[1] + (float)p3[1] + bb.y;
  float v2 = (float)p0[2] + (float)p1[2] + (float)p2[2] + (float)p3[2] + bb.z;
  float v3 = (float)p0[3] + (float)p1[3] + (float)p2[3] + (float)p3[3] + bb.w;
  o.x = en ? fmaf(g.x, v0, xm.x) : xm.x;
  o.y = en ? fmaf(g.y, v1, xm.y) : xm.y;
  o.z = en ? fmaf(g.z, v2, xm.z) : xm.z;
  o.w = en ? fmaf(g.w, v3, xm.w) : xm.w;
  *(float4*)(out + ro) = o;
}

// ---------------------------------------------------------------------------
extern "C" void kernel_launch(void* const* d_in, const int* in_sizes, int n_in,
                              void* d_out, int out_size, void* d_ws, size_t ws_size,
                              hipStream_t stream)
{
  const float* q_x    = (const float*)d_in[0];
  const float* kv_x   = (const float*)d_in[1];
  const float* t_cond = (const float*)d_in[2];
  const float* cos_q  = (const float*)d_in[3];
  const float* sin_q  = (const float*)d_in[4];
  const float* cos_k  = (const float*)d_in[5];
  const float* sin_k  = (const float*)d_in[6];
  const int*   grp    = (const int*)d_in[7];
  const int*   qen    = (const int*)d_in[8];
  const float* qn_w   = (const float*)d_in[9];
  const float* kvn_w  = (const float*)d_in[10];
  const float* n2_w   = (const float*)d_in[11];
  const float* Wq     = (const float*)d_in[12];
  const float* Wkv    = (const float*)d_in[13];
  const float* Wo     = (const float*)d_in[14];
  const float* W1     = (const float*)d_in[15];
  const float* b1     = (const float*)d_in[16];
  const float* W2     = (const float*)d_in[17];
  const float* b2     = (const float*)d_in[18];
  const float* adaW   = (const float*)d_in[19];
  const float* adab   = (const float*)d_in[20];
  float* out = (float*)d_out;

  char* ws = (char*)d_ws;
  const size_t MB = 1ull << 20;
  float*  mod    = (float*)(ws + 0);                  // 96 KB, whole call
  bf16_t* Wq_t   = (bf16_t*)(ws + 98304);             // 2 MB
  bf16_t* Wkv_t  = (bf16_t*)(ws + 98304 + 2 * MB);    // 4 MB
  bf16_t* Wo_t   = (bf16_t*)(ws + 98304 + 6 * MB);    // 2 MB
  bf16_t* W1_t   = (bf16_t*)(ws + 98304 + 8 * MB);    // 8 MB
  bf16_t* W2_t   = (bf16_t*)(ws + 98304 + 16 * MB);   // 8 MB
  bf16_t* qn_mod = (bf16_t*)(ws + 98304 + 24 * MB);   // 8 MB; reused as xn_mod
  bf16_t* kvn    = (bf16_t*)(ws + 98304 + 32 * MB);   // 8 MB; reused as attn_o
  bf16_t* q_r    = (bf16_t*)(ws + 98304 + 40 * MB);   // 8 MB; [q_r,k_r] reused as xbuf
  bf16_t* k_r    = (bf16_t*)(ws + 98304 + 48 * MB);   // 8 MB
  bf16_t* v_t    = (bf16_t*)(ws + 98304 + 56 * MB);   // 8 MB
  bf16_t* h1     = (bf16_t*)(ws + 98304 + 64 * MB);   // 32 MB
  bf16_t* scr    = (bf16_t*)(ws + 98304 + 96 * MB);   // 32 MB bf16 split-K partials
  bf16_t* xn_mod = qn_mod;
  bf16_t* attn_o = kvn;
  float*  xbuf   = (float*)q_r;

  // 1. adaLN modulation (split-K + atomics)
  mod_init_kernel<<<96, 256, 0, stream>>>(adab, mod);
  mod_partial_kernel<<<dim3(24, 8), 256, 0, stream>>>(t_cond, adaW, mod);
  // 2. weight prep (transpose + bf16)
  transpose_to_bf16<<<dim3(32, 32),  dim3(32, 8), 0, stream>>>(Wq,  Wq_t,  1024, 1024);
  transpose_to_bf16<<<dim3(64, 32),  dim3(32, 8), 0, stream>>>(Wkv, Wkv_t, 1024, 2048);
  transpose_to_bf16<<<dim3(32, 32),  dim3(32, 8), 0, stream>>>(Wo,  Wo_t,  1024, 1024);
  transpose_to_bf16<<<dim3(128, 32), dim3(32, 8), 0, stream>>>(W1,  W1_t,  1024, 4096);
  transpose_to_bf16<<<dim3(32, 128), dim3(32, 8), 0, stream>>>(W2,  W2_t,  4096, 1024);
  // 3. LayerNorms
  ln_mod_kernel<<<4096, 256, 0, stream>>>(q_x,  qn_w,  mod, 1, 0, 1024, qn_mod);
  ln_mod_kernel<<<4096, 256, 0, stream>>>(kv_x, kvn_w, mod, 0, 0, 0,    kvn);
  // 4. Q proj (split-2) + reduce/RoPE
  gemm_bt<4><<<dim3(8, 32, 2), 256, 0, stream>>>(qn_mod, Wq_t, 4096, 1024, 1024, 512,
                                                 scr, nullptr);
  reduce_q_rope_kernel<<<8192, 256, 0, stream>>>(scr, scr + 4194304, cos_q, sin_q, q_r);
  // 5. KV proj (split-2) + reduce/RoPE/V-transpose
  gemm_bt<4><<<dim3(16, 32, 2), 256, 0, stream>>>(kvn, Wkv_t, 4096, 2048, 1024, 512,
                                                  scr, nullptr);
  reduce_kv_kernel<<<dim3(64, 16), 256, 0, stream>>>(scr, scr + 8388608, cos_k, sin_k,
                                                     k_r, v_t);
  // 6. attention (128-row Q tiles)
  attn_kernel<<<dim3(64, 8), 256, 0, stream>>>(q_r, k_r, v_t, grp, attn_o);
  // 7. output proj (split-2) + fused reduce/gate/residual/LN2
  gemm_bt<4><<<dim3(8, 32, 2), 256, 0, stream>>>(attn_o, Wo_t, 4096, 1024, 1024, 512,
                                                 scr, nullptr);
  ln2_fused_kernel<<<4096, 256, 0, stream>>>(scr, scr + 4194304, q_x, n2_w, mod, qen,
                                             xbuf, xn_mod);
  // 8. MLP up + gelu
  gemm_bt<1><<<dim3(32, 32, 1), 256, 0, stream>>>(xn_mod, W1_t, 4096, 4096, 1024, 1024,
                                                  h1, b1);
  // 9. MLP down (split-4) + final fused reduce -> out
  gemm_bt<4><<<dim3(8, 32, 4), 256, 0, stream>>>(h1, W2_t, 4096, 1024, 4096, 1024,
                                                 scr, nullptr);
  final_reduce_kernel<<<4096, 256, 0, stream>>>(scr, b2, mod, qen, xbuf, out);
}

// Round 5
// 436.511 us; speedup vs baseline: 1.4187x; 1.0337x over previous
//
#include <hip/hip_runtime.h>
#include <hip/hip_bf16.h>
#include <math.h>

typedef __bf16 bf16_t;
typedef __attribute__((ext_vector_type(8))) __bf16 bf16x8;
typedef __attribute__((ext_vector_type(4))) __bf16 bf16x4;
typedef __attribute__((ext_vector_type(4))) float f32x4;

// ---------------------------------------------------------------------------
// mod init: mod[b][c] = adab[c]
// ---------------------------------------------------------------------------
__global__ __launch_bounds__(256) void mod_init_kernel(
    const float* __restrict__ adab, float* __restrict__ mod)
{
  int i = blockIdx.x * 256 + threadIdx.x;  // < 24576
  int c = i % 6144;
  mod[i] = adab[c];
}

// ---------------------------------------------------------------------------
// mod partial: split-K over the 1024 reduction dim, atomicAdd into mod.
// grid (24, 8) x 256
// ---------------------------------------------------------------------------
__global__ __launch_bounds__(256) void mod_partial_kernel(
    const float* __restrict__ tc, const float* __restrict__ adaW,
    float* __restrict__ mod)
{
  __shared__ float st[4][128];
  int tid = threadIdx.x, z = blockIdx.y;
  for (int i = tid; i < 512; i += 256)
    st[i >> 7][i & 127] = tc[(i >> 7) * 1024 + z * 128 + (i & 127)];
  __syncthreads();
  int col = blockIdx.x * 256 + tid;
  float a0 = 0.f, a1 = 0.f, a2 = 0.f, a3 = 0.f;
  for (int k = 0; k < 128; ++k) {
    float wv = adaW[(size_t)(z * 128 + k) * 6144 + col];
    a0 = fmaf(st[0][k], wv, a0);
    a1 = fmaf(st[1][k], wv, a1);
    a2 = fmaf(st[2][k], wv, a2);
    a3 = fmaf(st[3][k], wv, a3);
  }
  atomicAdd(&mod[col], a0);
  atomicAdd(&mod[6144 + col], a1);
  atomicAdd(&mod[2 * 6144 + col], a2);
  atomicAdd(&mod[3 * 6144 + col], a3);
}

// ---------------------------------------------------------------------------
// Transposing f32 -> bf16 weight prep: out[c][r] = (bf16) in[r][c]
// ---------------------------------------------------------------------------
__global__ __launch_bounds__(256) void transpose_to_bf16(
    const float* __restrict__ in, bf16_t* __restrict__ out, int R, int C)
{
  __shared__ float tile[32][33];
  int c0 = blockIdx.x * 32, r0 = blockIdx.y * 32;
  int tx = threadIdx.x, ty = threadIdx.y;
#pragma unroll
  for (int i = 0; i < 4; ++i)
    tile[ty + i * 8][tx] = in[(size_t)(r0 + ty + i * 8) * C + c0 + tx];
  __syncthreads();
#pragma unroll
  for (int i = 0; i < 4; ++i)
    out[(size_t)(c0 + ty + i * 8) * R + r0 + tx] = (bf16_t)tile[tx][ty + i * 8];
}

// ---------------------------------------------------------------------------
// LayerNorm (+ optional adaLN shift/scale) -> bf16.  One block per row (D=1024).
// ---------------------------------------------------------------------------
__global__ __launch_bounds__(256) void ln_mod_kernel(
    const float* __restrict__ x, const float* __restrict__ wgt,
    const float* __restrict__ mod, int useMod, int shOff, int scOff,
    bf16_t* __restrict__ out)
{
  int row = blockIdx.x;
  int b = row >> 10;
  int tid = threadIdx.x;
  const float* xr = x + (size_t)row * 1024;
  float4 v = ((const float4*)xr)[tid];
  float s = v.x + v.y + v.z + v.w;
  float s2 = v.x * v.x + v.y * v.y + v.z * v.z + v.w * v.w;
#pragma unroll
  for (int off = 32; off > 0; off >>= 1) {
    s += __shfl_down(s, off, 64);
    s2 += __shfl_down(s2, off, 64);
  }
  __shared__ float ps[4], ps2[4];
  if ((tid & 63) == 0) { ps[tid >> 6] = s; ps2[tid >> 6] = s2; }
  __syncthreads();
  float mu = (ps[0] + ps[1] + ps[2] + ps[3]) * (1.0f / 1024.0f);
  float var = (ps2[0] + ps2[1] + ps2[2] + ps2[3]) * (1.0f / 1024.0f) - mu * mu;
  float rs = rsqrtf(var + 1e-5f);
  float xv[4] = {v.x, v.y, v.z, v.w};
#pragma unroll
  for (int i = 0; i < 4; ++i) {
    int col = tid * 4 + i;
    float n = (xv[i] - mu) * rs * wgt[col];
    if (useMod)
      n = n * (1.0f + mod[b * 6144 + scOff + col]) + mod[b * 6144 + shOff + col];
    out[(size_t)row * 1024 + col] = (bf16_t)n;
  }
}

// ---------------------------------------------------------------------------
// Reduce split-K bf16 partials of Q proj + RoPE + scale -> q_r (B,H,S,64) bf16
// ---------------------------------------------------------------------------
__global__ __launch_bounds__(256) void reduce_q_rope_kernel(
    const bf16_t* __restrict__ P0, const bf16_t* __restrict__ P1,
    const float* __restrict__ cosq, const float* __restrict__ sinq,
    bf16_t* __restrict__ qr)
{
  int t = blockIdx.x * 256 + threadIdx.x;  // < 2M
  int hd = t & 31;
  int h = (t >> 5) & 15;
  int s = (t >> 9) & 1023;
  int b = t >> 19;
  size_t base = ((size_t)(b * 1024 + s)) * 1024 + h * 64 + hd;
  float v1 = (float)P0[base] + (float)P1[base];
  float v2 = (float)P0[base + 32] + (float)P1[base + 32];
  float c1 = cosq[s * 64 + hd], s1 = sinq[s * 64 + hd];
  float c2 = cosq[s * 64 + hd + 32], s2 = sinq[s * 64 + hd + 32];
  float o1 = (v1 * c1 - v2 * s1) * 0.125f;
  float o2 = (v2 * c2 + v1 * s2) * 0.125f;
  size_t ob = ((size_t)(b * 16 + h) * 1024 + s) * 64 + hd;
  qr[ob] = (bf16_t)o1;
  qr[ob + 32] = (bf16_t)o2;
}

// ---------------------------------------------------------------------------
// Reduce split-K bf16 partials of KV proj: RoPE on K -> k_r (B,H,K,64);
// V transposed via LDS -> v_t (B,H,64,K).  grid (64 bh, 16 ntile) x 256
// ---------------------------------------------------------------------------
__global__ __launch_bounds__(256) void reduce_kv_kernel(
    const bf16_t* __restrict__ P0, const bf16_t* __restrict__ P1,
    const float* __restrict__ cosk, const float* __restrict__ sink,
    bf16_t* __restrict__ kr, bf16_t* __restrict__ vt)
{
  __shared__ float ks[64][65];
  __shared__ float vs[64][65];
  int bh = blockIdx.x;
  int b = bh >> 4, h = bh & 15;
  int n0 = blockIdx.y * 64;
  int tid = threadIdx.x;
#pragma unroll
  for (int it = 0; it < 16; ++it) {
    int linear = tid + it * 256;
    int nl = linear >> 6, hd = linear & 63;
    size_t gi = ((size_t)(b * 1024 + n0 + nl)) * 2048 + h * 64 + hd;
    ks[nl][hd] = (float)P0[gi] + (float)P1[gi];
    vs[hd][nl] = (float)P0[gi + 1024] + (float)P1[gi + 1024];
  }
  __syncthreads();
#pragma unroll
  for (int it = 0; it < 16; ++it) {
    int linear = tid + it * 256;
    int nl = linear >> 6, hd = linear & 63;
    float kv = ks[nl][hd];
    float pv = ks[nl][hd ^ 32];
    float c = cosk[(n0 + nl) * 64 + hd], sn = sink[(n0 + nl) * 64 + hd];
    float o = (hd < 32) ? (kv * c - pv * sn) : (kv * c + pv * sn);
    kr[((size_t)bh * 1024 + n0 + nl) * 64 + hd] = (bf16_t)o;
    int rh = linear >> 6, nn = linear & 63;  // reuse for v store
    vt[((size_t)bh * 64 + rh) * 1024 + n0 + nn] = (bf16_t)vs[rh][nn];
  }
}

// ---------------------------------------------------------------------------
// Flash-style attention, NO online softmax (scores are O(1); softmax is
// shift-invariant, so accumulate exp(s) directly, normalize once at the end).
// 128-row Q tile per block; wave w owns rows [32w,32w+32) as 2 strips of 16.
// Ps region is wave-private -> no barrier between Ps write and PV read.
// ---------------------------------------------------------------------------
__global__ __launch_bounds__(256, 2) void attn_kernel(
    const bf16_t* __restrict__ qr, const bf16_t* __restrict__ kr,
    const bf16_t* __restrict__ vt, const int* __restrict__ grp,
    bf16_t* __restrict__ outp)
{
  __shared__ bf16_t Ks[64 * 72];
  __shared__ bf16_t Vs[64 * 72];
  __shared__ bf16_t Ps[128 * 72];
  __shared__ int gk[64];
  const int bh = blockIdx.x;
  const int b = bh >> 4, h = bh & 15;
  const int qBase = blockIdx.y * 128;
  const int tid = threadIdx.x, lane = tid & 63, w = tid >> 6;
  const int l15 = lane & 15, l4 = lane >> 4;
  const f32x4 zero = {0.f, 0.f, 0.f, 0.f};

  bf16x8 qA0[2], qA1[2];
  int gqr[2][4];
#pragma unroll
  for (int s = 0; s < 2; ++s) {
    int row = qBase + w * 32 + s * 16;
    const bf16_t* qp = qr + ((size_t)bh * 1024 + row + l15) * 64;
    qA0[s] = *(const bf16x8*)(qp + l4 * 8);
    qA1[s] = *(const bf16x8*)(qp + 32 + l4 * 8);
#pragma unroll
    for (int r = 0; r < 4; ++r) gqr[s][r] = grp[b * 1024 + row + l4 * 4 + r];
  }

  f32x4 oacc[2][4];
  float rsum[2][4];
#pragma unroll
  for (int s = 0; s < 2; ++s)
#pragma unroll
    for (int i = 0; i < 4; ++i) { oacc[s][i] = zero; rsum[s][i] = 0.f; }

  for (int kt = 0; kt < 16; ++kt) {
    __syncthreads();
#pragma unroll
    for (int i = 0; i < 2; ++i) {
      int c = tid * 2 + i;
      int r = c >> 3, cc = (c & 7) * 8;
      *(bf16x8*)(Ks + r * 72 + cc) =
          *(const bf16x8*)(kr + ((size_t)bh * 1024 + kt * 64 + r) * 64 + cc);
      *(bf16x8*)(Vs + r * 72 + cc) =
          *(const bf16x8*)(vt + ((size_t)bh * 64 + r) * 1024 + kt * 64 + cc);
    }
    if (tid < 64) gk[tid] = grp[b * 1024 + kt * 64 + tid];
    __syncthreads();

    int gkv[4];
    bf16x8 kf0[4], kf1[4];
#pragma unroll
    for (int nt = 0; nt < 4; ++nt) {
      gkv[nt] = gk[nt * 16 + l15];
      kf0[nt] = *(const bf16x8*)(Ks + (nt * 16 + l15) * 72 + l4 * 8);
      kf1[nt] = *(const bf16x8*)(Ks + (nt * 16 + l15) * 72 + 32 + l4 * 8);
    }

#pragma unroll
    for (int s = 0; s < 2; ++s) {
      f32x4 sacc[4];
#pragma unroll
      for (int nt = 0; nt < 4; ++nt) sacc[nt] = zero;
#pragma unroll
      for (int nt = 0; nt < 4; ++nt) {
        sacc[nt] = __builtin_amdgcn_mfma_f32_16x16x32_bf16(qA0[s], kf0[nt], sacc[nt], 0, 0, 0);
        sacc[nt] = __builtin_amdgcn_mfma_f32_16x16x32_bf16(qA1[s], kf1[nt], sacc[nt], 0, 0, 0);
      }
#pragma unroll
      for (int r = 0; r < 4; ++r) {
        int gq = gqr[s][r];
        float acc = 0.f;
#pragma unroll
        for (int nt = 0; nt < 4; ++nt) {
          float sv = sacc[nt][r] + ((gq == gkv[nt]) ? -60.f : 0.f);
          float p = __expf(sv);
          acc += p;
          Ps[(w * 32 + s * 16 + l4 * 4 + r) * 72 + nt * 16 + l15] = (bf16_t)p;
        }
        rsum[s][r] += acc;
      }
    }
    // no barrier: Ps rows [32w, 32w+32) are written and read by wave w only;
    // compiler's lgkmcnt tracking orders the ds_write -> ds_read dependency.
#pragma unroll
    for (int s = 0; s < 2; ++s) {
      const bf16_t* pp = Ps + (w * 32 + s * 16 + l15) * 72;
      bf16x8 pf0 = *(const bf16x8*)(pp + l4 * 8);
      bf16x8 pf1 = *(const bf16x8*)(pp + 32 + l4 * 8);
#pragma unroll
      for (int nt = 0; nt < 4; ++nt) {
        bf16x8 vf0 = *(const bf16x8*)(Vs + (nt * 16 + l15) * 72 + l4 * 8);
        bf16x8 vf1 = *(const bf16x8*)(Vs + (nt * 16 + l15) * 72 + 32 + l4 * 8);
        oacc[s][nt] = __builtin_amdgcn_mfma_f32_16x16x32_bf16(pf0, vf0, oacc[s][nt], 0, 0, 0);
        oacc[s][nt] = __builtin_amdgcn_mfma_f32_16x16x32_bf16(pf1, vf1, oacc[s][nt], 0, 0, 0);
      }
    }
  }

#pragma unroll
  for (int s = 0; s < 2; ++s)
#pragma unroll
    for (int r = 0; r < 4; ++r) {
      float t = rsum[s][r];
      t += __shfl_xor(t, 1, 64);
      t += __shfl_xor(t, 2, 64);
      t += __shfl_xor(t, 4, 64);
      t += __shfl_xor(t, 8, 64);
      rsum[s][r] = 1.f / t;
    }
#pragma unroll
  for (int s = 0; s < 2; ++s)
#pragma unroll
    for (int r = 0; r < 4; ++r) {
      int srow = qBase + w * 32 + s * 16 + l4 * 4 + r;
      float inv = rsum[s][r];
#pragma unroll
      for (int nt = 0; nt < 4; ++nt)
        outp[((size_t)(b * 1024 + srow)) * 1024 + h * 64 + nt * 16 + l15] =
            (bf16_t)(oacc[s][nt][r] * inv);
    }
}

// ---------------------------------------------------------------------------
// m97-style GEMM, BK=64 (half the barrier drains of BK=32), split-K
// (blockIdx.z), XOR-swizzled LDS (granule ^= row&7 on the global address;
// read side un-permutes -> 2-way bank access = free), XCD-aware tile map.
// EPI: 1 = bias+gelu->bf16,  4 = bf16 partial to Cb + z*M*N
// ---------------------------------------------------------------------------
__device__ __forceinline__ void stage16(const bf16_t* gp, bf16_t* lp) {
  __builtin_amdgcn_global_load_lds(
      (__attribute__((address_space(1))) void*)gp,
      (__attribute__((address_space(3))) void*)lp, 16, 0, 0);
}

template <int EPI>
__global__ __launch_bounds__(256, 2) void gemm_bt(
    const bf16_t* __restrict__ A, const bf16_t* __restrict__ Bt,
    int M, int N, int Kd, int kChunk,
    bf16_t* __restrict__ Cb,
    const float* __restrict__ bias)
{
  __shared__ bf16_t sA[128 * 64];
  __shared__ bf16_t sB[128 * 64];
  const int tid = threadIdx.x;
  const int lane = tid & 63, w = tid >> 6;
  const int wr = w >> 1, wc = w & 1;

  // XCD-aware tile remap (requires gy%4==0, gx%2==0)
  const int gx = gridDim.x, gy = gridDim.y;
  const int L = blockIdx.y * gx + blockIdx.x;
  const int xcd = L & 7, idx = L >> 3;
  const int ry = gy >> 2, rx = gx >> 1;
  const int tileY = (xcd & 3) * ry + (idx % ry);
  const int tileX = (xcd >> 2) * rx + (idx / ry);
  const int rowBase = tileY * 128;
  const int colBase = tileX * 128;

  const int l15 = lane & 15, l4 = lane >> 4;
  const int srow = lane >> 3;              // 0..7: row within an 8-row stage group
  const int sg = lane & 7;                 // granule slot
  const int scol = (sg ^ srow) * 8;        // swizzled global column (bf16 units)
  const int rl = l15 & 7;                  // row low bits for read un-permute
  const int g0 = (l4 ^ rl) * 8;            // lds granule, k-half 0
  const int g1 = ((4 + l4) ^ rl) * 8;      // lds granule, k-half 1

  const f32x4 zero = {0.f, 0.f, 0.f, 0.f};
  f32x4 acc[4][4];
#pragma unroll
  for (int i = 0; i < 4; ++i)
#pragma unroll
    for (int j = 0; j < 4; ++j) acc[i][j] = zero;

  const bf16_t* aBase = A + (size_t)(rowBase + w * 32 + srow) * Kd + scol;
  const bf16_t* bBase = Bt + (size_t)(colBase + w * 32 + srow) * Kd + scol;

  const int kStart = blockIdx.z * kChunk;
  for (int k0 = kStart; k0 < kStart + kChunk; k0 += 64) {
    __syncthreads();
#pragma unroll
    for (int i = 0; i < 4; ++i) {
      stage16(aBase + (size_t)i * 8 * Kd + k0, sA + (w * 32 + i * 8) * 64);
      stage16(bBase + (size_t)i * 8 * Kd + k0, sB + (w * 32 + i * 8) * 64);
    }
    __syncthreads();
    bf16x8 af[4], bfr[4];
    // k-half 0
#pragma unroll
    for (int mt = 0; mt < 4; ++mt)
      af[mt] = *(const bf16x8*)(sA + (wr * 64 + mt * 16 + l15) * 64 + g0);
#pragma unroll
    for (int nt = 0; nt < 4; ++nt)
      bfr[nt] = *(const bf16x8*)(sB + (wc * 64 + nt * 16 + l15) * 64 + g0);
#pragma unroll
    for (int mt = 0; mt < 4; ++mt)
#pragma unroll
      for (int nt = 0; nt < 4; ++nt)
        acc[mt][nt] = __builtin_amdgcn_mfma_f32_16x16x32_bf16(af[mt], bfr[nt],
                                                              acc[mt][nt], 0, 0, 0);
    // k-half 1
#pragma unroll
    for (int mt = 0; mt < 4; ++mt)
      af[mt] = *(const bf16x8*)(sA + (wr * 64 + mt * 16 + l15) * 64 + g1);
#pragma unroll
    for (int nt = 0; nt < 4; ++nt)
      bfr[nt] = *(const bf16x8*)(sB + (wc * 64 + nt * 16 + l15) * 64 + g1);
#pragma unroll
    for (int mt = 0; mt < 4; ++mt)
#pragma unroll
      for (int nt = 0; nt < 4; ++nt)
        acc[mt][nt] = __builtin_amdgcn_mfma_f32_16x16x32_bf16(af[mt], bfr[nt],
                                                              acc[mt][nt], 0, 0, 0);
  }

  const size_t zOff = (size_t)blockIdx.z * M * N;
#pragma unroll
  for (int mt = 0; mt < 4; ++mt) {
#pragma unroll
    for (int nt = 0; nt < 4; ++nt) {
      int col = colBase + wc * 64 + nt * 16 + l15;
#pragma unroll
      for (int r = 0; r < 4; ++r) {
        int rr = rowBase + wr * 64 + mt * 16 + l4 * 4 + r;
        float v = acc[mt][nt][r];
        if constexpr (EPI == 1) {
          float t = v + bias[col];
          float z = 0.7978845608028654f * (t + 0.044715f * t * t * t);
          float e = __expf(2.f * z);
          float g = 0.5f * t * (2.f - 2.f / (e + 1.f));
          Cb[(size_t)rr * N + col] = (bf16_t)g;
        } else {
          Cb[zOff + (size_t)rr * N + col] = (bf16_t)v;
        }
      }
    }
  }
}

// ---------------------------------------------------------------------------
// Fused: Wo split-K reduce + msa gate + residual + query gate -> xbuf (f32),
// then LN2 + mlp modulation -> xn_mod (bf16).  One block per row.
// ---------------------------------------------------------------------------
__global__ __launch_bounds__(256) void ln2_fused_kernel(
    const bf16_t* __restrict__ P0, const bf16_t* __restrict__ P1,
    const float* __restrict__ qx, const float* __restrict__ n2w,
    const float* __restrict__ mod, const int* __restrict__ qen,
    float* __restrict__ xbuf, bf16_t* __restrict__ xnmod)
{
  int row = blockIdx.x;
  int b = row >> 10;
  int tid = threadIdx.x;
  bool en = qen[row] != 0;
  bf16x4 p0 = *(const bf16x4*)(P0 + (size_t)row * 1024 + tid * 4);
  bf16x4 p1 = *(const bf16x4*)(P1 + (size_t)row * 1024 + tid * 4);
  float4 res = ((const float4*)(qx + (size_t)row * 1024))[tid];
  float4 g = ((const float4*)(mod + b * 6144 + 2048))[tid];
  float4 x;
  x.x = en ? fmaf(g.x, (float)p0[0] + (float)p1[0], res.x) : res.x;
  x.y = en ? fmaf(g.y, (float)p0[1] + (float)p1[1], res.y) : res.y;
  x.z = en ? fmaf(g.z, (float)p0[2] + (float)p1[2], res.z) : res.z;
  x.w = en ? fmaf(g.w, (float)p0[3] + (float)p1[3], res.w) : res.w;
  ((float4*)(xbuf + (size_t)row * 1024))[tid] = x;

  float s = x.x + x.y + x.z + x.w;
  float s2 = x.x * x.x + x.y * x.y + x.z * x.z + x.w * x.w;
#pragma unroll
  for (int off = 32; off > 0; off >>= 1) {
    s += __shfl_down(s, off, 64);
    s2 += __shfl_down(s2, off, 64);
  }
  __shared__ float ps[4], ps2[4];
  if ((tid & 63) == 0) { ps[tid >> 6] = s; ps2[tid >> 6] = s2; }
  __syncthreads();
  float mu = (ps[0] + ps[1] + ps[2] + ps[3]) * (1.0f / 1024.0f);
  float var = (ps2[0] + ps2[1] + ps2[2] + ps2[3]) * (1.0f / 1024.0f) - mu * mu;
  float rs = rsqrtf(var + 1e-5f);
  float4 sc = ((const float4*)(mod + b * 6144 + 4096))[tid];
  float4 sh = ((const float4*)(mod + b * 6144 + 3072))[tid];
  float4 wv = ((const float4*)n2w)[tid];
  float xv[4] = {x.x, x.y, x.z, x.w};
  float scv[4] = {sc.x, sc.y, sc.z, sc.w};
  float shv[4] = {sh.x, sh.y, sh.z, sh.w};
  float wvv[4] = {wv.x, wv.y, wv.z, wv.w};
#pragma unroll
  for (int i = 0; i < 4; ++i) {
    float n = (xv[i] - mu) * rs * wvv[i];
    n = n * (1.0f + scv[i]) + shv[i];
    xnmod[(size_t)row * 1024 + tid * 4 + i] = (bf16_t)n;
  }
}

// ---------------------------------------------------------------------------
// Final: W2 split-4 reduce + bias + mlp gate + residual + query gate -> out f32
// ---------------------------------------------------------------------------
__global__ __launch_bounds__(256) void final_reduce_kernel(
    const bf16_t* __restrict__ P, const float* __restrict__ b2,
    const float* __restrict__ mod, const int* __restrict__ qen,
    const float* __restrict__ xbuf, float* __restrict__ out)
{
  int row = blockIdx.x;
  int b = row >> 10;
  int tid = threadIdx.x;
  bool en = qen[row] != 0;
  size_t ro = (size_t)row * 1024 + tid * 4;
  bf16x4 p0 = *(const bf16x4*)(P + ro);
  bf16x4 p1 = *(const bf16x4*)(P + 4194304 + ro);
  bf16x4 p2 = *(const bf16x4*)(P + 2 * 4194304 + ro);
  bf16x4 p3 = *(const bf16x4*)(P + 3 * 4194304 + ro);
  float4 bb = ((const float4*)b2)[tid];
  float4 xm = *(const float4*)(xbuf + ro);
  float4 g = ((const float4*)(mod + b * 6144 + 5120))[tid];
  float4 o;
  float v0 = (float)p0[0] + (float)p1[0] + (float)p2[0] + (float)p3[0] + bb.x;
  float v1 = (float)p0[1] + (float)p1[1] + (float)p2[1] + (float)p3[1] + bb.y;
  float v2 = (float)p0[2] + (float)p1[2] + (float)p2[2] + (float)p3[2] + bb.z;
  float v3 = (float)p0[3] + (float)p1[3] + (float)p2[3] + (float)p3[3] + bb.w;
  o.x = en ? fmaf(g.x, v0, xm.x) : xm.x;
  o.y = en ? fmaf(g.y, v1, xm.y) : xm.y;
  o.z = en ? fmaf(g.z, v2, xm.z) : xm.z;
  o.w = en ? fmaf(g.w, v3, xm.w) : xm.w;
  *(float4*)(out + ro) = o;
}

// ---------------------------------------------------------------------------
extern "C" void kernel_launch(void* const* d_in, const int* in_sizes, int n_in,
                              void* d_out, int out_size, void* d_ws, size_t ws_size,
                              hipStream_t stream)
{
  const float* q_x    = (const float*)d_in[0];
  const float* kv_x   = (const float*)d_in[1];
  const float* t_cond = (const float*)d_in[2];
  const float* cos_q  = (const float*)d_in[3];
  const float* sin_q  = (const float*)d_in[4];
  const float* cos_k  = (const float*)d_in[5];
  const float* sin_k  = (const float*)d_in[6];
  const int*   grp    = (const int*)d_in[7];
  const int*   qen    = (const int*)d_in[8];
  const float* qn_w   = (const float*)d_in[9];
  const float* kvn_w  = (const float*)d_in[10];
  const float* n2_w   = (const float*)d_in[11];
  const float* Wq     = (const float*)d_in[12];
  const float* Wkv    = (const float*)d_in[13];
  const float* Wo     = (const float*)d_in[14];
  const float* W1     = (const float*)d_in[15];
  const float* b1     = (const float*)d_in[16];
  const float* W2     = (const float*)d_in[17];
  const float* b2     = (const float*)d_in[18];
  const float* adaW   = (const float*)d_in[19];
  const float* adab   = (const float*)d_in[20];
  float* out = (float*)d_out;

  char* ws = (char*)d_ws;
  const size_t MB = 1ull << 20;
  float*  mod    = (float*)(ws + 0);                  // 96 KB, whole call
  bf16_t* Wq_t   = (bf16_t*)(ws + 98304);             // 2 MB
  bf16_t* Wkv_t  = (bf16_t*)(ws + 98304 + 2 * MB);    // 4 MB
  bf16_t* Wo_t   = (bf16_t*)(ws + 98304 + 6 * MB);    // 2 MB
  bf16_t* W1_t   = (bf16_t*)(ws + 98304 + 8 * MB);    // 8 MB
  bf16_t* W2_t   = (bf16_t*)(ws + 98304 + 16 * MB);   // 8 MB
  bf16_t* qn_mod = (bf16_t*)(ws + 98304 + 24 * MB);   // 8 MB; reused as xn_mod
  bf16_t* kvn    = (bf16_t*)(ws + 98304 + 32 * MB);   // 8 MB; reused as attn_o
  bf16_t* q_r    = (bf16_t*)(ws + 98304 + 40 * MB);   // 8 MB; [q_r,k_r] reused as xbuf
  bf16_t* k_r    = (bf16_t*)(ws + 98304 + 48 * MB);   // 8 MB
  bf16_t* v_t    = (bf16_t*)(ws + 98304 + 56 * MB);   // 8 MB
  bf16_t* h1     = (bf16_t*)(ws + 98304 + 64 * MB);   // 32 MB
  bf16_t* scr    = (bf16_t*)(ws + 98304 + 96 * MB);   // 32 MB bf16 split-K partials
  bf16_t* xn_mod = qn_mod;
  bf16_t* attn_o = kvn;
  float*  xbuf   = (float*)q_r;

  // 1. adaLN modulation (split-K + atomics)
  mod_init_kernel<<<96, 256, 0, stream>>>(adab, mod);
  mod_partial_kernel<<<dim3(24, 8), 256, 0, stream>>>(t_cond, adaW, mod);
  // 2. weight prep (transpose + bf16)
  transpose_to_bf16<<<dim3(32, 32),  dim3(32, 8), 0, stream>>>(Wq,  Wq_t,  1024, 1024);
  transpose_to_bf16<<<dim3(64, 32),  dim3(32, 8), 0, stream>>>(Wkv, Wkv_t, 1024, 2048);
  transpose_to_bf16<<<dim3(32, 32),  dim3(32, 8), 0, stream>>>(Wo,  Wo_t,  1024, 1024);
  transpose_to_bf16<<<dim3(128, 32), dim3(32, 8), 0, stream>>>(W1,  W1_t,  1024, 4096);
  transpose_to_bf16<<<dim3(32, 128), dim3(32, 8), 0, stream>>>(W2,  W2_t,  4096, 1024);
  // 3. LayerNorms
  ln_mod_kernel<<<4096, 256, 0, stream>>>(q_x,  qn_w,  mod, 1, 0, 1024, qn_mod);
  ln_mod_kernel<<<4096, 256, 0, stream>>>(kv_x, kvn_w, mod, 0, 0, 0,    kvn);
  // 4. Q proj (split-2) + reduce/RoPE
  gemm_bt<4><<<dim3(8, 32, 2), 256, 0, stream>>>(qn_mod, Wq_t, 4096, 1024, 1024, 512,
                                                 scr, nullptr);
  reduce_q_rope_kernel<<<8192, 256, 0, stream>>>(scr, scr + 4194304, cos_q, sin_q, q_r);
  // 5. KV proj (split-2) + reduce/RoPE/V-transpose
  gemm_bt<4><<<dim3(16, 32, 2), 256, 0, stream>>>(kvn, Wkv_t, 4096, 2048, 1024, 512,
                                                  scr, nullptr);
  reduce_kv_kernel<<<dim3(64, 16), 256, 0, stream>>>(scr, scr + 8388608, cos_k, sin_k,
                                                     k_r, v_t);
  // 6. attention (128-row Q tiles)
  attn_kernel<<<dim3(64, 8), 256, 0, stream>>>(q_r, k_r, v_t, grp, attn_o);
  // 7. output proj (split-2) + fused reduce/gate/residual/LN2
  gemm_bt<4><<<dim3(8, 32, 2), 256, 0, stream>>>(attn_o, Wo_t, 4096, 1024, 1024, 512,
                                                 scr, nullptr);
  ln2_fused_kernel<<<4096, 256, 0, stream>>>(scr, scr + 4194304, q_x, n2_w, mod, qen,
                                             xbuf, xn_mod);
  // 8. MLP up + gelu
  gemm_bt<1><<<dim3(32, 32, 1), 256, 0, stream>>>(xn_mod, W1_t, 4096, 4096, 1024, 1024,
                                                  h1, b1);
  // 9. MLP down (split-4) + final fused reduce -> out
  gemm_bt<4><<<dim3(8, 32, 4), 256, 0, stream>>>(h1, W2_t, 4096, 1024, 4096, 1024,
                                                 scr, nullptr);
  final_reduce_kernel<<<4096, 256, 0, stream>>>(scr, b2, mod, qen, xbuf, out);
}

// Round 6
// 397.264 us; speedup vs baseline: 1.5589x; 1.0988x over previous
//
#include <hip/hip_runtime.h>
#include <hip/hip_bf16.h>
#include <math.h>

typedef __bf16 bf16_t;
typedef __attribute__((ext_vector_type(8))) __bf16 bf16x8;
typedef __attribute__((ext_vector_type(4))) __bf16 bf16x4;
typedef __attribute__((ext_vector_type(4))) float f32x4;

// ---------------------------------------------------------------------------
// Row compaction: idx[0..Mc) = enabled row ids (ascending), idx[Mc..4096)=0,
// *McPtr = Mc.  One block, 256 threads, 16 rows/thread.
// ---------------------------------------------------------------------------
__global__ __launch_bounds__(256) void compact_kernel(
    const int* __restrict__ qen, int* __restrict__ idx, int* __restrict__ McPtr)
{
  __shared__ int cnts[256];
  int t = threadIdx.x;
  int flags[16], c = 0;
#pragma unroll
  for (int i = 0; i < 16; ++i) {
    flags[i] = qen[t * 16 + i] != 0;
    c += flags[i];
  }
  cnts[t] = c;
  __syncthreads();
  for (int off = 1; off < 256; off <<= 1) {
    int v = cnts[t];
    if (t >= off) v += cnts[t - off];
    __syncthreads();
    cnts[t] = v;
    __syncthreads();
  }
  int p = cnts[t] - c;  // exclusive prefix
  int total = cnts[255];
#pragma unroll
  for (int i = 0; i < 16; ++i)
    if (flags[i]) idx[p++] = t * 16 + i;
  if (t == 0) *McPtr = total;
  for (int j = total + t; j < 4096; j += 256) idx[j] = 0;
}

// ---------------------------------------------------------------------------
// Disabled rows: out[row] = q_x[row] (exact per the gate algebra).
// ---------------------------------------------------------------------------
__global__ __launch_bounds__(256) void copy_disabled_kernel(
    const int* __restrict__ qen, const float* __restrict__ qx,
    float* __restrict__ out)
{
  int row = blockIdx.x;
  if (qen[row]) return;
  int tid = threadIdx.x;
  ((float4*)(out + (size_t)row * 1024))[tid] =
      ((const float4*)(qx + (size_t)row * 1024))[tid];
}

// ---------------------------------------------------------------------------
// mod init + partial (split-K atomics)
// ---------------------------------------------------------------------------
__global__ __launch_bounds__(256) void mod_init_kernel(
    const float* __restrict__ adab, float* __restrict__ mod)
{
  int i = blockIdx.x * 256 + threadIdx.x;  // < 24576
  mod[i] = adab[i % 6144];
}

__global__ __launch_bounds__(256) void mod_partial_kernel(
    const float* __restrict__ tc, const float* __restrict__ adaW,
    float* __restrict__ mod)
{
  __shared__ float st[4][128];
  int tid = threadIdx.x, z = blockIdx.y;
  for (int i = tid; i < 512; i += 256)
    st[i >> 7][i & 127] = tc[(i >> 7) * 1024 + z * 128 + (i & 127)];
  __syncthreads();
  int col = blockIdx.x * 256 + tid;
  float a0 = 0.f, a1 = 0.f, a2 = 0.f, a3 = 0.f;
  for (int k = 0; k < 128; ++k) {
    float wv = adaW[(size_t)(z * 128 + k) * 6144 + col];
    a0 = fmaf(st[0][k], wv, a0);
    a1 = fmaf(st[1][k], wv, a1);
    a2 = fmaf(st[2][k], wv, a2);
    a3 = fmaf(st[3][k], wv, a3);
  }
  atomicAdd(&mod[col], a0);
  atomicAdd(&mod[6144 + col], a1);
  atomicAdd(&mod[2 * 6144 + col], a2);
  atomicAdd(&mod[3 * 6144 + col], a3);
}

// ---------------------------------------------------------------------------
// All five weight transposes (f32 -> bf16, out[c][r]=in[r][c]) in ONE launch.
// grid = 12288 x (32,8)
// ---------------------------------------------------------------------------
__global__ __launch_bounds__(256) void transpose_all(
    const float* __restrict__ Wq, const float* __restrict__ Wkv,
    const float* __restrict__ Wo, const float* __restrict__ W1,
    const float* __restrict__ W2,
    bf16_t* __restrict__ oWq, bf16_t* __restrict__ oWkv,
    bf16_t* __restrict__ oWo, bf16_t* __restrict__ oW1,
    bf16_t* __restrict__ oW2)
{
  __shared__ float tile[32][33];
  int bid = blockIdx.x;
  const float* in; bf16_t* out; int R, C, gx, local;
  if (bid < 1024)      { in = Wq;  out = oWq;  R = 1024; C = 1024; gx = 32;  local = bid; }
  else if (bid < 3072) { in = Wkv; out = oWkv; R = 1024; C = 2048; gx = 64;  local = bid - 1024; }
  else if (bid < 4096) { in = Wo;  out = oWo;  R = 1024; C = 1024; gx = 32;  local = bid - 3072; }
  else if (bid < 8192) { in = W1;  out = oW1;  R = 1024; C = 4096; gx = 128; local = bid - 4096; }
  else                 { in = W2;  out = oW2;  R = 4096; C = 1024; gx = 32;  local = bid - 8192; }
  int c0 = (local % gx) * 32, r0 = (local / gx) * 32;
  int tx = threadIdx.x, ty = threadIdx.y;
#pragma unroll
  for (int i = 0; i < 4; ++i)
    tile[ty + i * 8][tx] = in[(size_t)(r0 + ty + i * 8) * C + c0 + tx];
  __syncthreads();
#pragma unroll
  for (int i = 0; i < 4; ++i)
    out[(size_t)(c0 + ty + i * 8) * R + r0 + tx] = (bf16_t)tile[tx][ty + i * 8];
}

// ---------------------------------------------------------------------------
// Both input LayerNorms in one launch: rows [0,4096) = q side (+msa mod),
// rows [4096,8192) = kv side (plain).
// ---------------------------------------------------------------------------
__global__ __launch_bounds__(256) void ln_both_kernel(
    const float* __restrict__ qx, const float* __restrict__ kvx,
    const float* __restrict__ qnw, const float* __restrict__ kvnw,
    const float* __restrict__ mod,
    bf16_t* __restrict__ qn_out, bf16_t* __restrict__ kvn_out)
{
  int rowg = blockIdx.x;
  bool isQ = rowg < 4096;
  int row = isQ ? rowg : rowg - 4096;
  int b = row >> 10;
  int tid = threadIdx.x;
  const float* x = (isQ ? qx : kvx) + (size_t)row * 1024;
  const float* wgt = isQ ? qnw : kvnw;
  bf16_t* outp = (isQ ? qn_out : kvn_out) + (size_t)row * 1024;

  float4 v = ((const float4*)x)[tid];
  float s = v.x + v.y + v.z + v.w;
  float s2 = v.x * v.x + v.y * v.y + v.z * v.z + v.w * v.w;
#pragma unroll
  for (int off = 32; off > 0; off >>= 1) {
    s += __shfl_down(s, off, 64);
    s2 += __shfl_down(s2, off, 64);
  }
  __shared__ float ps[4], ps2[4];
  if ((tid & 63) == 0) { ps[tid >> 6] = s; ps2[tid >> 6] = s2; }
  __syncthreads();
  float mu = (ps[0] + ps[1] + ps[2] + ps[3]) * (1.0f / 1024.0f);
  float var = (ps2[0] + ps2[1] + ps2[2] + ps2[3]) * (1.0f / 1024.0f) - mu * mu;
  float rs = rsqrtf(var + 1e-5f);
  float xv[4] = {v.x, v.y, v.z, v.w};
#pragma unroll
  for (int i = 0; i < 4; ++i) {
    int col = tid * 4 + i;
    float n = (xv[i] - mu) * rs * wgt[col];
    if (isQ)
      n = n * (1.0f + mod[b * 6144 + 1024 + col]) + mod[b * 6144 + col];
    outp[col] = (bf16_t)n;
  }
}

// ---------------------------------------------------------------------------
// Reduce split-K bf16 partials of Q proj + RoPE + scale -> q_r (B,H,S,64)
// ---------------------------------------------------------------------------
__global__ __launch_bounds__(256) void reduce_q_rope_kernel(
    const bf16_t* __restrict__ P0, const bf16_t* __restrict__ P1,
    const float* __restrict__ cosq, const float* __restrict__ sinq,
    bf16_t* __restrict__ qr)
{
  int t = blockIdx.x * 256 + threadIdx.x;  // < 2M
  int hd = t & 31;
  int h = (t >> 5) & 15;
  int s = (t >> 9) & 1023;
  int b = t >> 19;
  size_t base = ((size_t)(b * 1024 + s)) * 1024 + h * 64 + hd;
  float v1 = (float)P0[base] + (float)P1[base];
  float v2 = (float)P0[base + 32] + (float)P1[base + 32];
  float c1 = cosq[s * 64 + hd], s1 = sinq[s * 64 + hd];
  float c2 = cosq[s * 64 + hd + 32], s2 = sinq[s * 64 + hd + 32];
  float o1 = (v1 * c1 - v2 * s1) * 0.125f;
  float o2 = (v2 * c2 + v1 * s2) * 0.125f;
  size_t ob = ((size_t)(b * 16 + h) * 1024 + s) * 64 + hd;
  qr[ob] = (bf16_t)o1;
  qr[ob + 32] = (bf16_t)o2;
}

// ---------------------------------------------------------------------------
// Reduce split-K bf16 partials of KV proj: RoPE K -> k_r; V^T -> v_t.
// ---------------------------------------------------------------------------
__global__ __launch_bounds__(256) void reduce_kv_kernel(
    const bf16_t* __restrict__ P0, const bf16_t* __restrict__ P1,
    const float* __restrict__ cosk, const float* __restrict__ sink,
    bf16_t* __restrict__ kr, bf16_t* __restrict__ vt)
{
  __shared__ float ks[64][65];
  __shared__ float vs[64][65];
  int bh = blockIdx.x;
  int b = bh >> 4, h = bh & 15;
  int n0 = blockIdx.y * 64;
  int tid = threadIdx.x;
#pragma unroll
  for (int it = 0; it < 16; ++it) {
    int linear = tid + it * 256;
    int nl = linear >> 6, hd = linear & 63;
    size_t gi = ((size_t)(b * 1024 + n0 + nl)) * 2048 + h * 64 + hd;
    ks[nl][hd] = (float)P0[gi] + (float)P1[gi];
    vs[hd][nl] = (float)P0[gi + 1024] + (float)P1[gi + 1024];
  }
  __syncthreads();
#pragma unroll
  for (int it = 0; it < 16; ++it) {
    int linear = tid + it * 256;
    int nl = linear >> 6, hd = linear & 63;
    float kv = ks[nl][hd];
    float pv = ks[nl][hd ^ 32];
    float c = cosk[(n0 + nl) * 64 + hd], sn = sink[(n0 + nl) * 64 + hd];
    float o = (hd < 32) ? (kv * c - pv * sn) : (kv * c + pv * sn);
    kr[((size_t)bh * 1024 + n0 + nl) * 64 + hd] = (bf16_t)o;
    vt[((size_t)bh * 64 + nl) * 1024 + n0 + hd] = (bf16_t)vs[nl][hd];
  }
}

// ---------------------------------------------------------------------------
// Flash-style attention (no online softmax; exp-accumulate + one normalize).
// ---------------------------------------------------------------------------
__global__ __launch_bounds__(256, 2) void attn_kernel(
    const bf16_t* __restrict__ qr, const bf16_t* __restrict__ kr,
    const bf16_t* __restrict__ vt, const int* __restrict__ grp,
    bf16_t* __restrict__ outp)
{
  __shared__ bf16_t Ks[64 * 72];
  __shared__ bf16_t Vs[64 * 72];
  __shared__ bf16_t Ps[128 * 72];
  __shared__ int gk[64];
  const int bh = blockIdx.x;
  const int b = bh >> 4, h = bh & 15;
  const int qBase = blockIdx.y * 128;
  const int tid = threadIdx.x, lane = tid & 63, w = tid >> 6;
  const int l15 = lane & 15, l4 = lane >> 4;
  const f32x4 zero = {0.f, 0.f, 0.f, 0.f};

  bf16x8 qA0[2], qA1[2];
  int gqr[2][4];
#pragma unroll
  for (int s = 0; s < 2; ++s) {
    int row = qBase + w * 32 + s * 16;
    const bf16_t* qp = qr + ((size_t)bh * 1024 + row + l15) * 64;
    qA0[s] = *(const bf16x8*)(qp + l4 * 8);
    qA1[s] = *(const bf16x8*)(qp + 32 + l4 * 8);
#pragma unroll
    for (int r = 0; r < 4; ++r) gqr[s][r] = grp[b * 1024 + row + l4 * 4 + r];
  }

  f32x4 oacc[2][4];
  float rsum[2][4];
#pragma unroll
  for (int s = 0; s < 2; ++s)
#pragma unroll
    for (int i = 0; i < 4; ++i) { oacc[s][i] = zero; rsum[s][i] = 0.f; }

  for (int kt = 0; kt < 16; ++kt) {
    __syncthreads();
#pragma unroll
    for (int i = 0; i < 2; ++i) {
      int c = tid * 2 + i;
      int r = c >> 3, cc = (c & 7) * 8;
      *(bf16x8*)(Ks + r * 72 + cc) =
          *(const bf16x8*)(kr + ((size_t)bh * 1024 + kt * 64 + r) * 64 + cc);
      *(bf16x8*)(Vs + r * 72 + cc) =
          *(const bf16x8*)(vt + ((size_t)bh * 64 + r) * 1024 + kt * 64 + cc);
    }
    if (tid < 64) gk[tid] = grp[b * 1024 + kt * 64 + tid];
    __syncthreads();

    int gkv[4];
    bf16x8 kf0[4], kf1[4];
#pragma unroll
    for (int nt = 0; nt < 4; ++nt) {
      gkv[nt] = gk[nt * 16 + l15];
      kf0[nt] = *(const bf16x8*)(Ks + (nt * 16 + l15) * 72 + l4 * 8);
      kf1[nt] = *(const bf16x8*)(Ks + (nt * 16 + l15) * 72 + 32 + l4 * 8);
    }

#pragma unroll
    for (int s = 0; s < 2; ++s) {
      f32x4 sacc[4];
#pragma unroll
      for (int nt = 0; nt < 4; ++nt) sacc[nt] = zero;
#pragma unroll
      for (int nt = 0; nt < 4; ++nt) {
        sacc[nt] = __builtin_amdgcn_mfma_f32_16x16x32_bf16(qA0[s], kf0[nt], sacc[nt], 0, 0, 0);
        sacc[nt] = __builtin_amdgcn_mfma_f32_16x16x32_bf16(qA1[s], kf1[nt], sacc[nt], 0, 0, 0);
      }
#pragma unroll
      for (int r = 0; r < 4; ++r) {
        int gq = gqr[s][r];
        float acc = 0.f;
#pragma unroll
        for (int nt = 0; nt < 4; ++nt) {
          float sv = sacc[nt][r] + ((gq == gkv[nt]) ? -60.f : 0.f);
          float p = __expf(sv);
          acc += p;
          Ps[(w * 32 + s * 16 + l4 * 4 + r) * 72 + nt * 16 + l15] = (bf16_t)p;
        }
        rsum[s][r] += acc;
      }
    }
    // Ps rows are wave-private; compiler lgkmcnt orders write->read.
#pragma unroll
    for (int s = 0; s < 2; ++s) {
      const bf16_t* pp = Ps + (w * 32 + s * 16 + l15) * 72;
      bf16x8 pf0 = *(const bf16x8*)(pp + l4 * 8);
      bf16x8 pf1 = *(const bf16x8*)(pp + 32 + l4 * 8);
#pragma unroll
      for (int nt = 0; nt < 4; ++nt) {
        bf16x8 vf0 = *(const bf16x8*)(Vs + (nt * 16 + l15) * 72 + l4 * 8);
        bf16x8 vf1 = *(const bf16x8*)(Vs + (nt * 16 + l15) * 72 + 32 + l4 * 8);
        oacc[s][nt] = __builtin_amdgcn_mfma_f32_16x16x32_bf16(pf0, vf0, oacc[s][nt], 0, 0, 0);
        oacc[s][nt] = __builtin_amdgcn_mfma_f32_16x16x32_bf16(pf1, vf1, oacc[s][nt], 0, 0, 0);
      }
    }
  }

#pragma unroll
  for (int s = 0; s < 2; ++s)
#pragma unroll
    for (int r = 0; r < 4; ++r) {
      float t = rsum[s][r];
      t += __shfl_xor(t, 1, 64);
      t += __shfl_xor(t, 2, 64);
      t += __shfl_xor(t, 4, 64);
      t += __shfl_xor(t, 8, 64);
      rsum[s][r] = 1.f / t;
    }
#pragma unroll
  for (int s = 0; s < 2; ++s)
#pragma unroll
    for (int r = 0; r < 4; ++r) {
      int srow = qBase + w * 32 + s * 16 + l4 * 4 + r;
      float inv = rsum[s][r];
#pragma unroll
      for (int nt = 0; nt < 4; ++nt)
        outp[((size_t)(b * 1024 + srow)) * 1024 + h * 64 + nt * 16 + l15] =
            (bf16_t)(oacc[s][nt][r] * inv);
    }
}

// ---------------------------------------------------------------------------
// Shared GEMM guts: BK=64, XOR-swizzled LDS, 128x128 tile.
// ---------------------------------------------------------------------------
__device__ __forceinline__ void stage16(const bf16_t* gp, bf16_t* lp) {
  __builtin_amdgcn_global_load_lds(
      (__attribute__((address_space(1))) void*)gp,
      (__attribute__((address_space(3))) void*)lp, 16, 0, 0);
}

// Full GEMM (patch XCD map) — used for Wq / Wkv projections. EPI4: bf16
// partials at z*M*N.
__global__ __launch_bounds__(256, 2) void gemm_bt_full(
    const bf16_t* __restrict__ A, const bf16_t* __restrict__ Bt,
    int M, int N, int Kd, int kChunk, bf16_t* __restrict__ Cb)
{
  __shared__ bf16_t sA[128 * 64];
  __shared__ bf16_t sB[128 * 64];
  const int tid = threadIdx.x;
  const int lane = tid & 63, w = tid >> 6;
  const int wr = w >> 1, wc = w & 1;

  const int gx = gridDim.x, gy = gridDim.y;
  const int L = blockIdx.y * gx + blockIdx.x;
  const int xcd = L & 7, id2 = L >> 3;
  const int ry = gy >> 2, rx = gx >> 1;
  const int tileY = (xcd & 3) * ry + (id2 % ry);
  const int tileX = (xcd >> 2) * rx + (id2 / ry);
  const int rowBase = tileY * 128;
  const int colBase = tileX * 128;

  const int l15 = lane & 15, l4 = lane >> 4;
  const int srow = lane >> 3;
  const int sg = lane & 7;
  const int scol = (sg ^ srow) * 8;
  const int rl = l15 & 7;
  const int g0 = (l4 ^ rl) * 8;
  const int g1 = ((4 + l4) ^ rl) * 8;

  const f32x4 zero = {0.f, 0.f, 0.f, 0.f};
  f32x4 acc[4][4];
#pragma unroll
  for (int i = 0; i < 4; ++i)
#pragma unroll
    for (int j = 0; j < 4; ++j) acc[i][j] = zero;

  const bf16_t* aBase = A + (size_t)(rowBase + w * 32 + srow) * Kd + scol;
  const bf16_t* bBase = Bt + (size_t)(colBase + w * 32 + srow) * Kd + scol;

  const int kStart = blockIdx.z * kChunk;
  for (int k0 = kStart; k0 < kStart + kChunk; k0 += 64) {
    __syncthreads();
#pragma unroll
    for (int i = 0; i < 4; ++i) {
      stage16(aBase + (size_t)i * 8 * Kd + k0, sA + (w * 32 + i * 8) * 64);
      stage16(bBase + (size_t)i * 8 * Kd + k0, sB + (w * 32 + i * 8) * 64);
    }
    __syncthreads();
    bf16x8 af[4], bfr[4];
#pragma unroll
    for (int mt = 0; mt < 4; ++mt)
      af[mt] = *(const bf16x8*)(sA + (wr * 64 + mt * 16 + l15) * 64 + g0);
#pragma unroll
    for (int nt = 0; nt < 4; ++nt)
      bfr[nt] = *(const bf16x8*)(sB + (wc * 64 + nt * 16 + l15) * 64 + g0);
#pragma unroll
    for (int mt = 0; mt < 4; ++mt)
#pragma unroll
      for (int nt = 0; nt < 4; ++nt)
        acc[mt][nt] = __builtin_amdgcn_mfma_f32_16x16x32_bf16(af[mt], bfr[nt],
                                                              acc[mt][nt], 0, 0, 0);
#pragma unroll
    for (int mt = 0; mt < 4; ++mt)
      af[mt] = *(const bf16x8*)(sA + (wr * 64 + mt * 16 + l15) * 64 + g1);
#pragma unroll
    for (int nt = 0; nt < 4; ++nt)
      bfr[nt] = *(const bf16x8*)(sB + (wc * 64 + nt * 16 + l15) * 64 + g1);
#pragma unroll
    for (int mt = 0; mt < 4; ++mt)
#pragma unroll
      for (int nt = 0; nt < 4; ++nt)
        acc[mt][nt] = __builtin_amdgcn_mfma_f32_16x16x32_bf16(af[mt], bfr[nt],
                                                              acc[mt][nt], 0, 0, 0);
  }

  const size_t zOff = (size_t)blockIdx.z * M * N;
#pragma unroll
  for (int mt = 0; mt < 4; ++mt)
#pragma unroll
    for (int nt = 0; nt < 4; ++nt) {
      int col = colBase + wc * 64 + nt * 16 + l15;
#pragma unroll
      for (int r = 0; r < 4; ++r) {
        int rr = rowBase + wr * 64 + mt * 16 + l4 * 4 + r;
        Cb[zOff + (size_t)rr * N + col] = (bf16_t)acc[mt][nt][r];
      }
    }
}

// Compacted GEMM (row-owner XCD map; blocks past Mc exit).
// GATHER: A rows via idxG.  EPI: 1 = bias+gelu->Cb, 4 = bf16 partial at
// z*4096*N (fixed 4096-row padding so addressing is static).
template <int EPI, int GATHER>
__global__ __launch_bounds__(256, 2) void gemm_bt_c(
    const bf16_t* __restrict__ A, const bf16_t* __restrict__ Bt,
    int N, int Kd, int kChunk, bf16_t* __restrict__ Cb,
    const float* __restrict__ bias,
    const int* __restrict__ idxG, const int* __restrict__ McPtr)
{
  __shared__ bf16_t sA[128 * 64];
  __shared__ bf16_t sB[128 * 64];
  const int Mc = *McPtr;
  const int gx = gridDim.x;
  const int L = blockIdx.y * gx + blockIdx.x;
  const int xcd = L & 7, id2 = L >> 3;
  const int tileY = (id2 / gx) * 8 + xcd;
  const int tileX = id2 % gx;
  const int rowBase = tileY * 128;
  if (rowBase >= Mc) return;
  const int colBase = tileX * 128;

  const int tid = threadIdx.x;
  const int lane = tid & 63, w = tid >> 6;
  const int wr = w >> 1, wc = w & 1;
  const int l15 = lane & 15, l4 = lane >> 4;
  const int srow = lane >> 3;
  const int sg = lane & 7;
  const int scol = (sg ^ srow) * 8;
  const int rl = l15 & 7;
  const int g0 = (l4 ^ rl) * 8;
  const int g1 = ((4 + l4) ^ rl) * 8;

  const f32x4 zero = {0.f, 0.f, 0.f, 0.f};
  f32x4 acc[4][4];
#pragma unroll
  for (int i = 0; i < 4; ++i)
#pragma unroll
    for (int j = 0; j < 4; ++j) acc[i][j] = zero;

  const bf16_t* aB[4];
#pragma unroll
  for (int i = 0; i < 4; ++i) {
    int rowc = rowBase + w * 32 + i * 8 + srow;
    int arow = GATHER ? idxG[rowc] : rowc;
    aB[i] = A + (size_t)arow * Kd + scol;
  }
  const bf16_t* bBase = Bt + (size_t)(colBase + w * 32 + srow) * Kd + scol;

  const int kStart = blockIdx.z * kChunk;
  for (int k0 = kStart; k0 < kStart + kChunk; k0 += 64) {
    __syncthreads();
#pragma unroll
    for (int i = 0; i < 4; ++i) {
      stage16(aB[i] + k0, sA + (w * 32 + i * 8) * 64);
      stage16(bBase + (size_t)i * 8 * Kd + k0, sB + (w * 32 + i * 8) * 64);
    }
    __syncthreads();
    bf16x8 af[4], bfr[4];
#pragma unroll
    for (int mt = 0; mt < 4; ++mt)
      af[mt] = *(const bf16x8*)(sA + (wr * 64 + mt * 16 + l15) * 64 + g0);
#pragma unroll
    for (int nt = 0; nt < 4; ++nt)
      bfr[nt] = *(const bf16x8*)(sB + (wc * 64 + nt * 16 + l15) * 64 + g0);
#pragma unroll
    for (int mt = 0; mt < 4; ++mt)
#pragma unroll
      for (int nt = 0; nt < 4; ++nt)
        acc[mt][nt] = __builtin_amdgcn_mfma_f32_16x16x32_bf16(af[mt], bfr[nt],
                                                              acc[mt][nt], 0, 0, 0);
#pragma unroll
    for (int mt = 0; mt < 4; ++mt)
      af[mt] = *(const bf16x8*)(sA + (wr * 64 + mt * 16 + l15) * 64 + g1);
#pragma unroll
    for (int nt = 0; nt < 4; ++nt)
      bfr[nt] = *(const bf16x8*)(sB + (wc * 64 + nt * 16 + l15) * 64 + g1);
#pragma unroll
    for (int mt = 0; mt < 4; ++mt)
#pragma unroll
      for (int nt = 0; nt < 4; ++nt)
        acc[mt][nt] = __builtin_amdgcn_mfma_f32_16x16x32_bf16(af[mt], bfr[nt],
                                                              acc[mt][nt], 0, 0, 0);
  }

  const size_t zOff = (size_t)blockIdx.z * 4096 * N;
#pragma unroll
  for (int mt = 0; mt < 4; ++mt)
#pragma unroll
    for (int nt = 0; nt < 4; ++nt) {
      int col = colBase + wc * 64 + nt * 16 + l15;
#pragma unroll
      for (int r = 0; r < 4; ++r) {
        int rr = rowBase + wr * 64 + mt * 16 + l4 * 4 + r;  // compacted row
        float v = acc[mt][nt][r];
        if constexpr (EPI == 1) {
          float t = v + bias[col];
          float z = 0.7978845608028654f * (t + 0.044715f * t * t * t);
          float e = __expf(2.f * z);
          float g = 0.5f * t * (2.f - 2.f / (e + 1.f));
          Cb[(size_t)rr * N + col] = (bf16_t)g;
        } else {
          Cb[zOff + (size_t)rr * N + col] = (bf16_t)v;
        }
      }
    }
}

// ---------------------------------------------------------------------------
// Compacted: Wo split-4 reduce + msa gate + residual -> xbuf_c (f32), then
// LN2 + mlp modulation -> xn_c (bf16).  blockIdx = compacted row.
// ---------------------------------------------------------------------------
__global__ __launch_bounds__(256) void ln2_fused_kernel(
    const bf16_t* __restrict__ P, const float* __restrict__ qx,
    const float* __restrict__ n2w, const float* __restrict__ mod,
    const int* __restrict__ idxG, const int* __restrict__ McPtr,
    float* __restrict__ xbufc, bf16_t* __restrict__ xnc)
{
  int rowc = blockIdx.x;
  if (rowc >= *McPtr) return;
  int rr = idxG[rowc];
  int b = rr >> 10;
  int tid = threadIdx.x;
  size_t rc = (size_t)rowc * 1024 + tid * 4;
  bf16x4 p0 = *(const bf16x4*)(P + rc);
  bf16x4 p1 = *(const bf16x4*)(P + 4194304 + rc);
  bf16x4 p2 = *(const bf16x4*)(P + 2 * 4194304 + rc);
  bf16x4 p3 = *(const bf16x4*)(P + 3 * 4194304 + rc);
  float4 res = ((const float4*)(qx + (size_t)rr * 1024))[tid];
  float4 g = ((const float4*)(mod + b * 6144 + 2048))[tid];
  float4 x;
  x.x = fmaf(g.x, (float)p0[0] + (float)p1[0] + (float)p2[0] + (float)p3[0], res.x);
  x.y = fmaf(g.y, (float)p0[1] + (float)p1[1] + (float)p2[1] + (float)p3[1], res.y);
  x.z = fmaf(g.z, (float)p0[2] + (float)p1[2] + (float)p2[2] + (float)p3[2], res.z);
  x.w = fmaf(g.w, (float)p0[3] + (float)p1[3] + (float)p2[3] + (float)p3[3], res.w);
  *(float4*)(xbufc + rc) = x;

  float s = x.x + x.y + x.z + x.w;
  float s2 = x.x * x.x + x.y * x.y + x.z * x.z + x.w * x.w;
#pragma unroll
  for (int off = 32; off > 0; off >>= 1) {
    s += __shfl_down(s, off, 64);
    s2 += __shfl_down(s2, off, 64);
  }
  __shared__ float ps[4], ps2[4];
  if ((tid & 63) == 0) { ps[tid >> 6] = s; ps2[tid >> 6] = s2; }
  __syncthreads();
  float mu = (ps[0] + ps[1] + ps[2] + ps[3]) * (1.0f / 1024.0f);
  float var = (ps2[0] + ps2[1] + ps2[2] + ps2[3]) * (1.0f / 1024.0f) - mu * mu;
  float rs = rsqrtf(var + 1e-5f);
  float4 sc = ((const float4*)(mod + b * 6144 + 4096))[tid];
  float4 sh = ((const float4*)(mod + b * 6144 + 3072))[tid];
  float4 wv = ((const float4*)n2w)[tid];
  float xv[4] = {x.x, x.y, x.z, x.w};
  float scv[4] = {sc.x, sc.y, sc.z, sc.w};
  float shv[4] = {sh.x, sh.y, sh.z, sh.w};
  float wvv[4] = {wv.x, wv.y, wv.z, wv.w};
#pragma unroll
  for (int i = 0; i < 4; ++i) {
    float n = (xv[i] - mu) * rs * wvv[i];
    n = n * (1.0f + scv[i]) + shv[i];
    xnc[(size_t)rowc * 1024 + tid * 4 + i] = (bf16_t)n;
  }
}

// ---------------------------------------------------------------------------
// Compacted final: W2 split-4 reduce + bias + mlp gate + residual -> out[rr]
// ---------------------------------------------------------------------------
__global__ __launch_bounds__(256) void final_reduce_kernel(
    const bf16_t* __restrict__ P, const float* __restrict__ b2,
    const float* __restrict__ mod, const int* __restrict__ idxG,
    const int* __restrict__ McPtr, const float* __restrict__ xbufc,
    float* __restrict__ out)
{
  int rowc = blockIdx.x;
  if (rowc >= *McPtr) return;
  int rr = idxG[rowc];
  int b = rr >> 10;
  int tid = threadIdx.x;
  size_t rc = (size_t)rowc * 1024 + tid * 4;
  bf16x4 p0 = *(const bf16x4*)(P + rc);
  bf16x4 p1 = *(const bf16x4*)(P + 4194304 + rc);
  bf16x4 p2 = *(const bf16x4*)(P + 2 * 4194304 + rc);
  bf16x4 p3 = *(const bf16x4*)(P + 3 * 4194304 + rc);
  float4 bb = ((const float4*)b2)[tid];
  float4 xm = *(const float4*)(xbufc + rc);
  float4 g = ((const float4*)(mod + b * 6144 + 5120))[tid];
  float v0 = (float)p0[0] + (float)p1[0] + (float)p2[0] + (float)p3[0] + bb.x;
  float v1 = (float)p0[1] + (float)p1[1] + (float)p2[1] + (float)p3[1] + bb.y;
  float v2 = (float)p0[2] + (float)p1[2] + (float)p2[2] + (float)p3[2] + bb.z;
  float v3 = (float)p0[3] + (float)p1[3] + (float)p2[3] + (float)p3[3] + bb.w;
  float4 o;
  o.x = fmaf(g.x, v0, xm.x);
  o.y = fmaf(g.y, v1, xm.y);
  o.z = fmaf(g.z, v2, xm.z);
  o.w = fmaf(g.w, v3, xm.w);
  *(float4*)(out + (size_t)rr * 1024 + tid * 4) = o;
}

// ---------------------------------------------------------------------------
extern "C" void kernel_launch(void* const* d_in, const int* in_sizes, int n_in,
                              void* d_out, int out_size, void* d_ws, size_t ws_size,
                              hipStream_t stream)
{
  const float* q_x    = (const float*)d_in[0];
  const float* kv_x   = (const float*)d_in[1];
  const float* t_cond = (const float*)d_in[2];
  const float* cos_q  = (const float*)d_in[3];
  const float* sin_q  = (const float*)d_in[4];
  const float* cos_k  = (const float*)d_in[5];
  const float* sin_k  = (const float*)d_in[6];
  const int*   grp    = (const int*)d_in[7];
  const int*   qen    = (const int*)d_in[8];
  const float* qn_w   = (const float*)d_in[9];
  const float* kvn_w  = (const float*)d_in[10];
  const float* n2_w   = (const float*)d_in[11];
  const float* Wq     = (const float*)d_in[12];
  const float* Wkv    = (const float*)d_in[13];
  const float* Wo     = (const float*)d_in[14];
  const float* W1     = (const float*)d_in[15];
  const float* b1     = (const float*)d_in[16];
  const float* W2     = (const float*)d_in[17];
  const float* b2     = (const float*)d_in[18];
  const float* adaW   = (const float*)d_in[19];
  const float* adab   = (const float*)d_in[20];
  float* out = (float*)d_out;

  char* ws = (char*)d_ws;
  const size_t MB = 1ull << 20;
  float*  mod    = (float*)(ws + 0);                   // 96 KB
  int*    idxL   = (int*)(ws + 98304);                 // 16 KB
  int*    McPtr  = (int*)(ws + 98304 + 16384);         // 4 B (pad to 128 KB)
  char*   wbase  = ws + 131072;
  bf16_t* Wq_t   = (bf16_t*)(wbase);                   // 2 MB
  bf16_t* Wkv_t  = (bf16_t*)(wbase + 2 * MB);          // 4 MB
  bf16_t* Wo_t   = (bf16_t*)(wbase + 6 * MB);          // 2 MB
  bf16_t* W1_t   = (bf16_t*)(wbase + 8 * MB);          // 8 MB
  bf16_t* W2_t   = (bf16_t*)(wbase + 16 * MB);         // 8 MB
  bf16_t* qn_mod = (bf16_t*)(wbase + 24 * MB);         // 8 MB; reused as xn_c
  bf16_t* kvn    = (bf16_t*)(wbase + 32 * MB);         // 8 MB; reused as attn_o
  bf16_t* q_r    = (bf16_t*)(wbase + 40 * MB);         // 8 MB; [q_r,k_r] reused xbuf_c
  bf16_t* k_r    = (bf16_t*)(wbase + 48 * MB);         // 8 MB
  bf16_t* v_t    = (bf16_t*)(wbase + 56 * MB);         // 8 MB
  bf16_t* h1     = (bf16_t*)(wbase + 64 * MB);         // 32 MB
  bf16_t* scr    = (bf16_t*)(wbase + 96 * MB);         // 32 MB split-K partials
  bf16_t* xn_c   = qn_mod;
  bf16_t* attn_o = kvn;
  float*  xbuf_c = (float*)q_r;

  // 0. row compaction + disabled-row passthrough
  compact_kernel<<<1, 256, 0, stream>>>(qen, idxL, McPtr);
  copy_disabled_kernel<<<4096, 256, 0, stream>>>(qen, q_x, out);
  // 1. adaLN modulation
  mod_init_kernel<<<96, 256, 0, stream>>>(adab, mod);
  mod_partial_kernel<<<dim3(24, 8), 256, 0, stream>>>(t_cond, adaW, mod);
  // 2. weight prep (all five transposes, one launch)
  transpose_all<<<12288, dim3(32, 8), 0, stream>>>(Wq, Wkv, Wo, W1, W2,
                                                   Wq_t, Wkv_t, Wo_t, W1_t, W2_t);
  // 3. both LayerNorms, one launch
  ln_both_kernel<<<8192, 256, 0, stream>>>(q_x, kv_x, qn_w, kvn_w, mod,
                                           qn_mod, kvn);
  // 4. Q proj (split-2) + reduce/RoPE
  gemm_bt_full<<<dim3(8, 32, 2), 256, 0, stream>>>(qn_mod, Wq_t, 4096, 1024, 1024,
                                                   512, scr);
  reduce_q_rope_kernel<<<8192, 256, 0, stream>>>(scr, scr + 4194304, cos_q, sin_q, q_r);
  // 5. KV proj (split-2) + reduce/RoPE/V-transpose
  gemm_bt_full<<<dim3(16, 32, 2), 256, 0, stream>>>(kvn, Wkv_t, 4096, 2048, 1024,
                                                    512, scr);
  reduce_kv_kernel<<<dim3(64, 16), 256, 0, stream>>>(scr, scr + 8388608, cos_k, sin_k,
                                                     k_r, v_t);
  // 6. attention (full rows)
  attn_kernel<<<dim3(64, 8), 256, 0, stream>>>(q_r, k_r, v_t, grp, attn_o);
  // 7. Wo proj: compacted rows, gathered A, split-4 partials
  gemm_bt_c<4, 1><<<dim3(8, 32, 4), 256, 0, stream>>>(attn_o, Wo_t, 1024, 1024, 256,
                                                      scr, nullptr, idxL, McPtr);
  // 8. compacted reduce + gate + residual + LN2
  ln2_fused_kernel<<<4096, 256, 0, stream>>>(scr, q_x, n2_w, mod, idxL, McPtr,
                                             xbuf_c, xn_c);
  // 9. MLP up + gelu (compacted, dense A)
  gemm_bt_c<1, 0><<<dim3(32, 32, 1), 256, 0, stream>>>(xn_c, W1_t, 4096, 1024, 1024,
                                                       h1, b1, idxL, McPtr);
  // 10. MLP down (compacted, split-4) + final reduce -> out
  gemm_bt_c<4, 0><<<dim3(8, 32, 4), 256, 0, stream>>>(h1, W2_t, 1024, 4096, 1024,
                                                      scr, nullptr, idxL, McPtr);
  final_reduce_kernel<<<4096, 256, 0, stream>>>(scr, b2, mod, idxL, McPtr, xbuf_c, out);
}